// Round 2
// baseline (711.198 us; speedup 1.0000x reference)
//
#include <hip/hip_runtime.h>
#include <hip/hip_bf16.h>
#include <stdint.h>

typedef __bf16 bf16x8 __attribute__((ext_vector_type(8)));
typedef float  f32x4  __attribute__((ext_vector_type(4)));

#define RATIO 0.08838834764831845f
#define EPSV  1e-4f

#define GLOBAL_AS __attribute__((address_space(1)))
#define LDS_AS    __attribute__((address_space(3)))

static __device__ __forceinline__ void gload16(const void* g, void* l) {
  __builtin_amdgcn_global_load_lds((GLOBAL_AS const void*)g, (LDS_AS void*)l, 16, 0, 0);
}

// ---------------- workspace layout (bytes) ----------------
static constexpr size_t OFF_XB    = 0;                        // 16384*128*2
static constexpr size_t OFF_WCAT  = OFF_XB    + 4194304;      // 384*128*2
static constexpr size_t OFF_MQ    = OFF_WCAT  + 98304;        // 1024*128*2
static constexpr size_t OFF_MK    = OFF_MQ    + 262144;
static constexpr size_t OFF_BCAT  = OFF_MK    + 262144;       // 384*4 (pad)
static constexpr size_t OFF_BQF   = OFF_BCAT  + 2048;         // 1024*4
static constexpr size_t OFF_BKF   = OFF_BQF   + 4096;
static constexpr size_t OFF_Y     = OFF_BKF   + 4096;         // 16384*384*4
static constexpr size_t OFF_QF    = OFF_Y     + 25165824;     // 8*2048*1024*2
static constexpr size_t OFF_KF    = OFF_QF    + 33554432;
static constexpr size_t OFF_KFT   = OFF_KF    + 33554432;
static constexpr size_t OFF_VFT   = OFF_KFT   + 33554432;     // 8*128*2048*2
static constexpr size_t OFF_KPART = OFF_VFT   + 4194304;      // 8*128*4
static constexpr size_t OFF_KMAX  = OFF_KPART + 4096;         // 64*4
static constexpr size_t OFF_KSUM  = OFF_KMAX  + 256;          // 8*1024*4
static constexpr size_t OFF_DINV  = OFF_KSUM  + 32768;        // 16384*4
static constexpr size_t OFF_CTXP  = OFF_DINV  + 65536;        // 4*8*128*1024*4
static constexpr size_t OFF_CTXT  = OFF_CTXP  + 16777216;     // 8*128*1024*2
static constexpr size_t WS_NEED   = OFF_CTXT  + 2097152;      // ~147 MiB

// ---------------- shared NT-GEMM core: C(128x128) = A(tm:,*) * B(tn:,*)^T ----
static __device__ __forceinline__ void gemm_core(
    const __hip_bfloat16* __restrict__ A, const __hip_bfloat16* __restrict__ B,
    int lda, int ldb, int K, int tm, int tn,
    __bf16* As, __bf16* Bs, f32x4 acc[4][4]) {
  const int t    = threadIdx.x;
  const int w    = t >> 6;
  const int lane = t & 63;
  const int m_off = (w >> 1) << 6;
  const int n_off = (w & 1) << 6;
  const int r0 = t >> 2;            // 0..63 staging row
  const int kk = (t & 3) << 3;      // 0,8,16,24
  char* Asb = (char*)As + (w << 10);
  char* Bsb = (char*)Bs + (w << 10);
  const int frow = lane & 15;
  const int koff = (lane >> 4) << 3;
  for (int k0 = 0; k0 < K; k0 += 32) {
    const __hip_bfloat16* Ag = A + (size_t)(tm + r0) * lda + (k0 + kk);
    const __hip_bfloat16* Bg = B + (size_t)(tn + r0) * ldb + (k0 + kk);
    gload16(Ag, Asb);
    gload16(Ag + (size_t)64 * lda, Asb + 4096);
    gload16(Bg, Bsb);
    gload16(Bg + (size_t)64 * ldb, Bsb + 4096);
    __syncthreads();
    bf16x8 af[4], bfr[4];
#pragma unroll
    for (int mi = 0; mi < 4; ++mi)
      af[mi] = *(const bf16x8*)(As + ((m_off + mi * 16 + frow) << 5) + koff);
#pragma unroll
    for (int ni = 0; ni < 4; ++ni)
      bfr[ni] = *(const bf16x8*)(Bs + ((n_off + ni * 16 + frow) << 5) + koff);
#pragma unroll
    for (int mi = 0; mi < 4; ++mi)
#pragma unroll
      for (int ni = 0; ni < 4; ++ni)
        acc[mi][ni] = __builtin_amdgcn_mfma_f32_16x16x32_bf16(af[mi], bfr[ni], acc[mi][ni], 0, 0, 0);
    __syncthreads();
  }
}

#define ZERO_ACC(acc) do {                                   \
  _Pragma("unroll") for (int a_ = 0; a_ < 4; ++a_)           \
  _Pragma("unroll") for (int b_ = 0; b_ < 4; ++b_)           \
    acc[a_][b_] = (f32x4){0.f, 0.f, 0.f, 0.f};               \
} while (0)

// ---------------- prep kernels ----------------
__global__ void k_prepwb(const float* __restrict__ Wq, const float* __restrict__ bq,
                         const float* __restrict__ Wk, const float* __restrict__ bk,
                         const float* __restrict__ Wv, const float* __restrict__ bv,
                         __hip_bfloat16* __restrict__ Wcat, float* __restrict__ bcat) {
  int i = blockIdx.x * 256 + threadIdx.x;
  if (i < 49152) {
    int mat = i >> 14, rem = i & 16383;
    const float* W = (mat == 0) ? Wq : ((mat == 1) ? Wk : Wv);
    Wcat[i] = __float2bfloat16(W[rem]);
  }
  if (i < 384) {
    int mat = i >> 7;
    const float* b = (mat == 0) ? bq : ((mat == 1) ? bk : bv);
    bcat[i] = b[i & 127];
  }
}

__global__ void k_prepM(const float* __restrict__ Wq, const float* __restrict__ bq,
                        const float* __restrict__ Wk, const float* __restrict__ bk,
                        const float* __restrict__ proj,
                        __hip_bfloat16* __restrict__ Mq, __hip_bfloat16* __restrict__ Mk,
                        float* __restrict__ bqf, float* __restrict__ bkf) {
  int i = blockIdx.x * 256 + threadIdx.x;
  if (i < 262144) {
    int which = i >> 17;
    int rem = i & 131071;
    int hj = rem >> 7, e = rem & 127;
    int hh = hj >> 7, j = hj & 127;
    const float* W = which ? Wk : Wq;
    float s = 0.f;
#pragma unroll
    for (int u = 0; u < 16; ++u) s += proj[j * 16 + u] * W[(hh * 16 + u) * 128 + e];
    if (which) Mk[rem] = __float2bfloat16(0.5f * s);
    else       Mq[rem] = __float2bfloat16(0.5f * s);
  }
  if (i < 2048) {
    int which = i >> 10;
    int hj = i & 1023, hh = hj >> 7, j = hj & 127;
    const float* b = which ? bk : bq;
    float s = 0.f;
#pragma unroll
    for (int u = 0; u < 16; ++u) s += proj[j * 16 + u] * b[hh * 16 + u];
    if (which) bkf[hj] = 0.5f * s;
    else       bqf[hj] = 0.5f * s;
  }
}

__global__ void k_convx(const float* __restrict__ x, __hip_bfloat16* __restrict__ xb) {
  int i = (blockIdx.x * 256 + threadIdx.x) * 4;
  f32x4 v = *(const f32x4*)(x + i);
#pragma unroll
  for (int j = 0; j < 4; ++j) xb[i + j] = __float2bfloat16(v[j]);
}

// ---------------- projection GEMM: Y = x*Wcat^T + bcat ----------------
__global__ __launch_bounds__(256) void k_proj(
    const __hip_bfloat16* __restrict__ xb, const __hip_bfloat16* __restrict__ Wcat,
    const float* __restrict__ bcat, float* __restrict__ Y) {
  __shared__ __align__(16) __bf16 As[4096], Bs[4096];
  const int tm = blockIdx.x << 7, tn = blockIdx.y << 7;
  f32x4 acc[4][4];
  ZERO_ACC(acc);
  gemm_core(xb, Wcat, 128, 128, 128, tm, tn, As, Bs, acc);
  const int t = threadIdx.x, w = t >> 6, lane = t & 63;
  const int m_off = (w >> 1) << 6, n_off = (w & 1) << 6;
#pragma unroll
  for (int ni = 0; ni < 4; ++ni) {
    const int col = tn + n_off + ni * 16 + (lane & 15);
    const float bias = bcat[col];
#pragma unroll
    for (int mi = 0; mi < 4; ++mi)
#pragma unroll
      for (int i = 0; i < 4; ++i) {
        const int row = tm + m_off + mi * 16 + ((lane >> 4) << 2) + i;
        Y[(size_t)row * 384 + col] = acc[mi][ni][i] + bias;
      }
  }
}

// ---------------- vfT build (tiled transpose) ----------------
// vfT[(h*128 + r*16 + a)*2048 + c] = Y[(r*2048 + c)*384 + 256 + h*16 + a]
__global__ void k_vft2(const float* __restrict__ Y, __hip_bfloat16* __restrict__ vfT) {
  const int cb = blockIdx.x, r = blockIdx.y, h = blockIdx.z;
  const int c0 = cb << 7;
  __shared__ float tile[16][132];
  const int t = threadIdx.x;
  const int a = t & 15, cc0 = t >> 4;
#pragma unroll
  for (int i = 0; i < 8; ++i) {
    const int cc = cc0 + (i << 4);
    tile[a][cc] = Y[(size_t)(r * 2048 + c0 + cc) * 384 + 256 + (h << 4) + a];
  }
  __syncthreads();
  const int row = t >> 4, cg = t & 15;
  bf16x8 v;
#pragma unroll
  for (int j = 0; j < 8; ++j) v[j] = (__bf16)tile[row][(cg << 3) + j];
  *(bf16x8*)(vfT + ((size_t)((h << 7) + (r << 4) + row) << 11) + c0 + (cg << 3)) = v;
}

// ---------------- q features ----------------
__global__ __launch_bounds__(256) void k_dashq(
    const __hip_bfloat16* __restrict__ xb, const __hip_bfloat16* __restrict__ Mq,
    const float* __restrict__ bqf, const float* __restrict__ Y,
    __hip_bfloat16* __restrict__ qf) {
  __shared__ __align__(16) __bf16 As[4096], Bs[4096];
  __shared__ float diag_s[128];
  __shared__ float rmax_s[2][128];
  const int h = blockIdx.y;
  const int tm = blockIdx.x << 7;
  f32x4 acc[4][4];
  ZERO_ACC(acc);
  gemm_core(xb, Mq + h * 16384, 128, 128, 128, tm, 0, As, Bs, acc);
  const int t = threadIdx.x, w = t >> 6, lane = t & 63;
  const int m_off = (w >> 1) << 6, n_off = (w & 1) << 6;
  if (t < 128) {
    const float* yp = Y + (size_t)(tm + t) * 384 + h * 16;
    float s = 0.f;
#pragma unroll
    for (int u = 0; u < 16; ++u) s += yp[u] * yp[u];
    diag_s[t] = 0.125f * s;
  }
  float bia[4];
#pragma unroll
  for (int ni = 0; ni < 4; ++ni) bia[ni] = bqf[h * 128 + n_off + ni * 16 + (lane & 15)];
  float rmx[4][4];
#pragma unroll
  for (int mi = 0; mi < 4; ++mi)
#pragma unroll
    for (int i = 0; i < 4; ++i) {
      float m0 = acc[mi][0][i] + bia[0];
      m0 = fmaxf(m0, acc[mi][1][i] + bia[1]);
      m0 = fmaxf(m0, acc[mi][2][i] + bia[2]);
      m0 = fmaxf(m0, acc[mi][3][i] + bia[3]);
      rmx[mi][i] = m0;
    }
#pragma unroll
  for (int off = 1; off < 16; off <<= 1)
#pragma unroll
    for (int mi = 0; mi < 4; ++mi)
#pragma unroll
      for (int i = 0; i < 4; ++i)
        rmx[mi][i] = fmaxf(rmx[mi][i], __shfl_xor(rmx[mi][i], off));
  if ((lane & 15) == 0) {
#pragma unroll
    for (int mi = 0; mi < 4; ++mi)
#pragma unroll
      for (int i = 0; i < 4; ++i)
        rmax_s[w & 1][m_off + mi * 16 + ((lane >> 4) << 2) + i] = rmx[mi][i];
  }
  __syncthreads();
#pragma unroll
  for (int mi = 0; mi < 4; ++mi) {
#pragma unroll
    for (int i = 0; i < 4; ++i) {
      const int rl = m_off + mi * 16 + ((lane >> 4) << 2) + i;
      const int rg = tm + rl;
      const int c = rg & 2047, r = rg >> 11;
      const float md = diag_s[rl] + fmaxf(rmax_s[0][rl], rmax_s[1][rl]);
#pragma unroll
      for (int ni = 0; ni < 4; ++ni) {
        const int j = n_off + ni * 16 + (lane & 15);
        const float f = RATIO * (__expf(acc[mi][ni][i] + bia[ni] - md) + EPSV);
        qf[((size_t)((h << 11) + c) << 10) + (r << 7) + j] = __float2bfloat16(f);
      }
    }
  }
}

// ---------------- k features: pass A (max) ----------------
__global__ __launch_bounds__(256) void k_dashk_max(
    const __hip_bfloat16* __restrict__ xb, const __hip_bfloat16* __restrict__ Mk,
    const float* __restrict__ bkf, float* __restrict__ kpart) {
  __shared__ __align__(16) __bf16 As[4096], Bs[4096];
  __shared__ float wmax[4];
  const int h = blockIdx.y;
  const int tm = blockIdx.x << 7;
  f32x4 acc[4][4];
  ZERO_ACC(acc);
  gemm_core(xb, Mk + h * 16384, 128, 128, 128, tm, 0, As, Bs, acc);
  const int t = threadIdx.x, w = t >> 6, lane = t & 63;
  const int n_off = (w & 1) << 6;
  float mx = -1e30f;
#pragma unroll
  for (int ni = 0; ni < 4; ++ni) {
    const float bia = bkf[h * 128 + n_off + ni * 16 + (lane & 15)];
#pragma unroll
    for (int mi = 0; mi < 4; ++mi)
#pragma unroll
      for (int i = 0; i < 4; ++i) mx = fmaxf(mx, acc[mi][ni][i] + bia);
  }
#pragma unroll
  for (int off = 1; off < 64; off <<= 1) mx = fmaxf(mx, __shfl_xor(mx, off));
  if (lane == 0) wmax[w] = mx;
  __syncthreads();
  if (t == 0) kpart[h * 128 + blockIdx.x] = fmaxf(fmaxf(wmax[0], wmax[1]), fmaxf(wmax[2], wmax[3]));
}

__global__ void k_kmaxred(const float* __restrict__ kpart, float* __restrict__ kmax) {
  const int t = threadIdx.x;  // 64
  const int r = t >> 3, h = t & 7;
  float m = -1e30f;
  for (int i = 0; i < 16; ++i) m = fmaxf(m, kpart[h * 128 + r * 16 + i]);
  kmax[r * 8 + h] = m;
}

// ---------------- k features: pass B (features, kf + kfT) ----------------
__global__ __launch_bounds__(256) void k_dashk_feat(
    const __hip_bfloat16* __restrict__ xb, const __hip_bfloat16* __restrict__ Mk,
    const float* __restrict__ bkf, const float* __restrict__ Y,
    const float* __restrict__ kmax,
    __hip_bfloat16* __restrict__ kf, __hip_bfloat16* __restrict__ kfT) {
  __shared__ __align__(16) __bf16 As[4096], Bs[4096];
  __shared__ float diag_s[128];
  __shared__ __align__(16) __bf16 kT[128 * 136];
  const int h = blockIdx.y;
  const int tm = blockIdx.x << 7;
  f32x4 acc[4][4];
  ZERO_ACC(acc);
  gemm_core(xb, Mk + h * 16384, 128, 128, 128, tm, 0, As, Bs, acc);
  const int t = threadIdx.x, w = t >> 6, lane = t & 63;
  const int m_off = (w >> 1) << 6, n_off = (w & 1) << 6;
  if (t < 128) {
    const float* yp = Y + (size_t)(tm + t) * 384 + 128 + h * 16;
    float s = 0.f;
#pragma unroll
    for (int u = 0; u < 16; ++u) s += yp[u] * yp[u];
    diag_s[t] = 0.125f * s;
  }
  const int r = tm >> 11;
  const int c0 = tm & 2047;
  const float m = kmax[r * 8 + h];
  float bia[4];
#pragma unroll
  for (int ni = 0; ni < 4; ++ni) bia[ni] = bkf[h * 128 + n_off + ni * 16 + (lane & 15)];
  __syncthreads();
#pragma unroll
  for (int mi = 0; mi < 4; ++mi) {
#pragma unroll
    for (int i = 0; i < 4; ++i) {
      const int rl = m_off + mi * 16 + ((lane >> 4) << 2) + i;
      const int c = c0 + rl;
      const float dm = diag_s[rl] + m;
#pragma unroll
      for (int ni = 0; ni < 4; ++ni) {
        const int j = n_off + ni * 16 + (lane & 15);
        const float f = RATIO * (__expf(acc[mi][ni][i] + bia[ni] - dm) + EPSV);
        kf[((size_t)((h << 11) + c) << 10) + (r << 7) + j] = __float2bfloat16(f);
        kT[j * 136 + rl] = (__bf16)f;
      }
    }
  }
  __syncthreads();
  const int j2 = t >> 1, half = t & 1;
  __bf16* dst = (__bf16*)kfT + (((size_t)(h << 10) + (r << 7) + j2) << 11) + c0 + (half << 6);
  const __bf16* srcr = kT + j2 * 136 + (half << 6);
#pragma unroll
  for (int q8 = 0; q8 < 8; ++q8)
    *(bf16x8*)(dst + (q8 << 3)) = *(const bf16x8*)(srcr + (q8 << 3));
}

// ---------------- k_sum / D_inv ----------------
__global__ void k_ksum(const __hip_bfloat16* __restrict__ kf, float* __restrict__ ksum) {
  const int h = blockIdx.y, d = blockIdx.x * 128 + threadIdx.x;
  const __hip_bfloat16* p = kf + ((size_t)h << 21) + d;
  float s = 0.f;
  for (int c = 0; c < 2048; ++c) s += __bfloat162float(p[(size_t)c << 10]);
  ksum[h * 1024 + d] = s;
}

__global__ __launch_bounds__(256) void k_dinv(
    const __hip_bfloat16* __restrict__ qf, const float* __restrict__ ksum,
    float* __restrict__ dinv) {
  const int t = threadIdx.x, w = t >> 6, lane = t & 63;
  const int h = blockIdx.y;
  const int c = blockIdx.x * 4 + w;
  const __bf16* qp = (const __bf16*)qf + ((size_t)((h << 11) + c) << 10);
  const float* ks = ksum + h * 1024;
  const int d0 = lane << 4;
  bf16x8 v0 = *(const bf16x8*)(qp + d0);
  bf16x8 v1 = *(const bf16x8*)(qp + d0 + 8);
  float s = 0.f;
#pragma unroll
  for (int j = 0; j < 8; ++j) s += (float)v0[j] * ks[d0 + j] + (float)v1[j] * ks[d0 + 8 + j];
#pragma unroll
  for (int off = 1; off < 64; off <<= 1) s += __shfl_xor(s, off);
  if (lane == 0) dinv[(h << 11) + c] = 1.0f / s;
}

// ---------------- attn GEMM: 256x256 tile, 8-phase counted-vmcnt pipeline ----
#define SBAR() __builtin_amdgcn_s_barrier()
#define FEN()  do { asm volatile("" ::: "memory"); __builtin_amdgcn_sched_barrier(0); } while (0)
#define PRIO1() __builtin_amdgcn_s_setprio(1)
#define PRIO0() __builtin_amdgcn_s_setprio(0)

// stage one 128x32 half-tile (1 gload16/thread), linear LDS dest,
// inverse-swizzled global source (T2 both-sides rule).
static __device__ __forceinline__ void stage_half(
    const __hip_bfloat16* __restrict__ G, int row0, int k0, char* ldstile, int half) {
  const int t = threadIdx.x;
  const int wid = t >> 6;
  const int sr = t >> 2;                                    // 0..127
  const int scol = (((t & 3) ^ ((t >> 3) & 3)) << 3);       // swizzle-inverse col
  gload16(G + (size_t)(row0 + half * 128 + sr) * 1024 + (k0 + scol),
          ldstile + half * 8192 + (wid << 10));
}

#define LDA4(dst, buf, qm) do {                                              \
  _Pragma("unroll") for (int mi_ = 0; mi_ < 4; ++mi_)                        \
    dst[mi_] = *(const bf16x8*)((buf) + (qm) * 8192 + mi_ * 1024 + abase);   \
} while (0)
#define LDB2(dst, buf, qn) do {                                              \
  _Pragma("unroll") for (int ni_ = 0; ni_ < 2; ++ni_)                        \
    dst[ni_] = *(const bf16x8*)((buf) + (qn) * 8192 + ni_ * 1024 + bbase);   \
} while (0)
#define MFMA8(ACC, AR, BR) do {                                              \
  _Pragma("unroll") for (int mi_ = 0; mi_ < 4; ++mi_)                        \
  _Pragma("unroll") for (int ni_ = 0; ni_ < 2; ++ni_)                        \
    ACC[mi_][ni_] = __builtin_amdgcn_mfma_f32_16x16x32_bf16(                 \
        AR[mi_], BR[ni_], ACC[mi_][ni_], 0, 0, 0);                           \
} while (0)

__global__ __launch_bounds__(512, 4) void k_attn8(
    const __hip_bfloat16* __restrict__ qf, const __hip_bfloat16* __restrict__ kf,
    float* __restrict__ attn) {
  __shared__ __align__(64) char lds[65536];  // A:[2][256][32]bf16 @0, B @32768
  // bijective XCD swizzle: 512 blocks, 64/XCD -> one head per XCD
  const int lid = ((blockIdx.z << 3) + blockIdx.y) * 8 + blockIdx.x;
  const int swz = ((lid & 7) << 6) + (lid >> 3);
  const int h  = swz >> 6;
  const int tm = (((swz >> 3) & 7) << 8);
  const int tn = ((swz & 7) << 8);
  const __hip_bfloat16* Ag = qf + ((size_t)h << 21);
  const __hip_bfloat16* Bg = kf + ((size_t)h << 21);

  const int t = threadIdx.x, wid = t >> 6, lane = t & 63;
  const int f = lane & 15;
  const int wr = wid >> 2, wc = wid & 3;
  const int colpart = (((lane >> 4) ^ ((lane >> 1) & 3)) << 4);  // T2 read swizzle
  const int abase = (wr * 64 + f) * 64 + colpart;
  const int bbase = (wc * 32 + f) * 64 + colpart;

  f32x4 acc00[4][2] = {}, acc01[4][2] = {}, acc10[4][2] = {}, acc11[4][2] = {};
  bf16x8 aR[4], bq0[2], bq1[2];

  // prologue: stage tile 0 into buf0 in consumption order [Ah0,Bh0,Bh1,Ah1]
  stage_half(Ag, tm, 0, lds, 0);
  stage_half(Bg, tn, 0, lds + 32768, 0);
  stage_half(Bg, tn, 0, lds + 32768, 1);
  stage_half(Ag, tm, 0, lds, 1);
  asm volatile("s_waitcnt vmcnt(2)" ::: "memory");
  SBAR(); FEN();

  for (int kt = 0; kt < 31; ++kt) {
    const int b = kt & 1;
    char* Ab = lds + b * 16384;
    char* Bb = lds + 32768 + b * 16384;
    char* An = lds + (b ^ 1) * 16384;
    char* Bn = lds + 32768 + (b ^ 1) * 16384;
    const int nk0 = (kt + 1) << 5;
    // phase 1: quadrant (qm0,qn0); prefetch Ah0(t+1)
    LDA4(aR, Ab, 0); LDB2(bq0, Bb, 0);
    stage_half(Ag, tm, nk0, An, 0);
    SBAR(); FEN();
    PRIO1(); MFMA8(acc00, aR, bq0); PRIO0();
    asm volatile("s_waitcnt vmcnt(2)" ::: "memory");
    SBAR(); FEN();
    // phase 2: (qm0,qn1); prefetch Bh0(t+1)
    LDB2(bq1, Bb, 1);
    stage_half(Bg, tn, nk0, Bn, 0);
    SBAR(); FEN();
    PRIO1(); MFMA8(acc01, aR, bq1); PRIO0();
    asm volatile("s_waitcnt vmcnt(2)" ::: "memory");
    SBAR(); FEN();
    // phase 3: (qm1,qn0); prefetch Bh1(t+1)
    LDA4(aR, Ab, 1);
    stage_half(Bg, tn, nk0, Bn, 1);
    SBAR(); FEN();
    PRIO1(); MFMA8(acc10, aR, bq0); PRIO0();
    SBAR(); FEN();
    // phase 4: (qm1,qn1); prefetch Ah1(t+1)
    stage_half(Ag, tm, nk0, An, 1);
    SBAR(); FEN();
    PRIO1(); MFMA8(acc11, aR, bq1); PRIO0();
    asm volatile("s_waitcnt vmcnt(2)" ::: "memory");
    SBAR(); FEN();
  }
  { // epilogue tile 31 (buf1), drain waits
    char* Ab = lds + 16384;
    char* Bb = lds + 32768 + 16384;
    LDA4(aR, Ab, 0); LDB2(bq0, Bb, 0);
    SBAR(); FEN();
    PRIO1(); MFMA8(acc00, aR, bq0); PRIO0();
    asm volatile("s_waitcnt vmcnt(1)" ::: "memory");
    SBAR(); FEN();
    LDB2(bq1, Bb, 1);
    SBAR(); FEN();
    PRIO1(); MFMA8(acc01, aR, bq1); PRIO0();
    asm volatile("s_waitcnt vmcnt(0)" ::: "memory");
    SBAR(); FEN();
    LDA4(aR, Ab, 1);
    SBAR(); FEN();
    PRIO1(); MFMA8(acc10, aR, bq0); PRIO0();
    SBAR(); FEN();
    PRIO1(); MFMA8(acc11, aR, bq1); PRIO0();
  }

  float* Cc = attn + ((size_t)h << 22);
  const int rbase = tm + wr * 64 + ((lane >> 4) << 2);
  const int cbase = tn + wc * 32 + f;
#pragma unroll
  for (int mi = 0; mi < 4; ++mi)
#pragma unroll
    for (int i = 0; i < 4; ++i) {
      float* r0 = Cc + ((size_t)(rbase + mi * 16 + i) << 11) + cbase;
      float* r1 = Cc + ((size_t)(rbase + 128 + mi * 16 + i) << 11) + cbase;
#pragma unroll
      for (int ni = 0; ni < 2; ++ni) {
        r0[ni * 16]       = acc00[mi][ni][i];
        r0[128 + ni * 16] = acc01[mi][ni][i];
        r1[ni * 16]       = acc10[mi][ni][i];
        r1[128 + ni * 16] = acc11[mi][ni][i];
      }
    }
}

// ---------------- context GEMM (K-split) ----------------
__global__ __launch_bounds__(256) void k_ctx(
    const __hip_bfloat16* __restrict__ vfT, const __hip_bfloat16* __restrict__ kfT,
    float* __restrict__ ctxp) {
  __shared__ __align__(16) __bf16 As[4096], Bs[4096];
  const int z = blockIdx.z, h = z >> 2, kc = z & 3;
  const int tn = blockIdx.y << 7;
  f32x4 acc[4][4];
  ZERO_ACC(acc);
  gemm_core(vfT + ((size_t)h << 18) + (kc << 9), kfT + ((size_t)h << 21) + (kc << 9),
            2048, 2048, 512, 0, tn, As, Bs, acc);
  float* Cp = ctxp + ((size_t)(kc * 8 + h) << 17);
  const int t = threadIdx.x, w = t >> 6, lane = t & 63;
  const int m_off = (w >> 1) << 6, n_off = (w & 1) << 6;
#pragma unroll
  for (int mi = 0; mi < 4; ++mi)
#pragma unroll
    for (int i = 0; i < 4; ++i) {
      const int row = m_off + mi * 16 + ((lane >> 4) << 2) + i;
#pragma unroll
      for (int ni = 0; ni < 4; ++ni) {
        const int col = tn + n_off + ni * 16 + (lane & 15);
        Cp[((size_t)row << 10) + col] = acc[mi][ni][i];
      }
    }
}

__global__ void k_ctxred(const float* __restrict__ ctxp, __hip_bfloat16* __restrict__ ctxT) {
  const int i = blockIdx.x * 256 + threadIdx.x;
  const float s = ctxp[i] + ctxp[i + 1048576] + ctxp[i + 2097152] + ctxp[i + 3145728];
  ctxT[i] = __float2bfloat16(s);
}

// ---------------- out GEMM + D_inv scale + scatter ----------------
__global__ __launch_bounds__(256) void k_out(
    const __hip_bfloat16* __restrict__ qf, const __hip_bfloat16* __restrict__ ctxT,
    const float* __restrict__ dinv, float* __restrict__ outp) {
  __shared__ __align__(16) __bf16 As[4096], Bs[4096];
  const int h = blockIdx.z;
  const int tm = blockIdx.x << 7;
  f32x4 acc[4][4];
  ZERO_ACC(acc);
  gemm_core(qf + ((size_t)h << 21), ctxT + ((size_t)h << 17), 1024, 1024, 1024, tm, 0, As, Bs, acc);
  const int t = threadIdx.x, w = t >> 6, lane = t & 63;
  const int m_off = (w >> 1) << 6, n_off = (w & 1) << 6;
#pragma unroll
  for (int mi = 0; mi < 4; ++mi)
#pragma unroll
    for (int i = 0; i < 4; ++i) {
      const int row = tm + m_off + mi * 16 + ((lane >> 4) << 2) + i;
      const float dv = dinv[(h << 11) + row];
#pragma unroll
      for (int ni = 0; ni < 4; ++ni) {
        const int col = n_off + ni * 16 + (lane & 15);
        const int rb = col >> 4, tt = col & 15;
        outp[(((size_t)(rb << 11) + row) << 7) + (h << 4) + tt] = acc[mi][ni][i] * dv;
      }
    }
}

// ---------------- launch ----------------
extern "C" void kernel_launch(void* const* d_in, const int* in_sizes, int n_in,
                              void* d_out, int out_size, void* d_ws, size_t ws_size,
                              hipStream_t stream) {
  const float* x    = (const float*)d_in[0];
  const float* Wq   = (const float*)d_in[1];
  const float* bq   = (const float*)d_in[2];
  const float* Wk   = (const float*)d_in[3];
  const float* bk   = (const float*)d_in[4];
  const float* Wv   = (const float*)d_in[5];
  const float* bv   = (const float*)d_in[6];
  const float* proj = (const float*)d_in[7];
  if (ws_size < WS_NEED) return;

  char* ws = (char*)d_ws;
  __hip_bfloat16* xb   = (__hip_bfloat16*)(ws + OFF_XB);
  __hip_bfloat16* Wcat = (__hip_bfloat16*)(ws + OFF_WCAT);
  __hip_bfloat16* Mq   = (__hip_bfloat16*)(ws + OFF_MQ);
  __hip_bfloat16* Mk   = (__hip_bfloat16*)(ws + OFF_MK);
  float* bcat = (float*)(ws + OFF_BCAT);
  float* bqf  = (float*)(ws + OFF_BQF);
  float* bkf  = (float*)(ws + OFF_BKF);
  float* Y    = (float*)(ws + OFF_Y);
  __hip_bfloat16* qf  = (__hip_bfloat16*)(ws + OFF_QF);
  __hip_bfloat16* kf  = (__hip_bfloat16*)(ws + OFF_KF);
  __hip_bfloat16* kfT = (__hip_bfloat16*)(ws + OFF_KFT);
  __hip_bfloat16* vfT = (__hip_bfloat16*)(ws + OFF_VFT);
  float* kpart = (float*)(ws + OFF_KPART);
  float* kmax  = (float*)(ws + OFF_KMAX);
  float* ksum  = (float*)(ws + OFF_KSUM);
  float* dinv  = (float*)(ws + OFF_DINV);
  float* ctxp  = (float*)(ws + OFF_CTXP);
  __hip_bfloat16* ctxT = (__hip_bfloat16*)(ws + OFF_CTXT);

  float* outp = (float*)d_out;
  float* attn = (float*)d_out + 2097152;

  k_prepwb<<<dim3(192), dim3(256), 0, stream>>>(Wq, bq, Wk, bk, Wv, bv, Wcat, bcat);
  k_prepM<<<dim3(1024), dim3(256), 0, stream>>>(Wq, bq, Wk, bk, proj, Mq, Mk, bqf, bkf);
  k_convx<<<dim3(2048), dim3(256), 0, stream>>>(x, xb);
  k_proj<<<dim3(128, 3), dim3(256), 0, stream>>>(xb, Wcat, bcat, Y);
  k_vft2<<<dim3(16, 8, 8), dim3(256), 0, stream>>>(Y, vfT);
  k_dashq<<<dim3(128, 8), dim3(256), 0, stream>>>(xb, Mq, bqf, Y, qf);
  k_dashk_max<<<dim3(128, 8), dim3(256), 0, stream>>>(xb, Mk, bkf, kpart);
  k_kmaxred<<<dim3(1), dim3(64), 0, stream>>>(kpart, kmax);
  k_dashk_feat<<<dim3(128, 8), dim3(256), 0, stream>>>(xb, Mk, bkf, Y, kmax, kf, kfT);
  k_ksum<<<dim3(8, 8), dim3(128), 0, stream>>>(kf, ksum);
  k_dinv<<<dim3(512, 8), dim3(256), 0, stream>>>(qf, ksum, dinv);
  k_attn8<<<dim3(8, 8, 8), dim3(512), 0, stream>>>(qf, kf, attn);
  k_ctx<<<dim3(1, 8, 32), dim3(256), 0, stream>>>(vfT, kfT, ctxp);
  k_ctxred<<<dim3(4096), dim3(256), 0, stream>>>(ctxp, ctxT);
  k_out<<<dim3(16, 1, 8), dim3(256), 0, stream>>>(qf, ctxT, dinv, outp);
}

// Round 3
// 214.976 us; speedup vs baseline: 3.3083x; 3.3083x over previous
//
#include <hip/hip_runtime.h>
#include <hip/hip_bf16.h>
#include <stdint.h>

typedef __bf16 bf16x8 __attribute__((ext_vector_type(8)));
typedef float  f32x4  __attribute__((ext_vector_type(4)));

#define RATIO 0.08838834764831845f
#define EPSV  1e-4f

#define GLOBAL_AS __attribute__((address_space(1)))
#define LDS_AS    __attribute__((address_space(3)))

static __device__ __forceinline__ void gload16(const void* g, void* l) {
  __builtin_amdgcn_global_load_lds((GLOBAL_AS const void*)g, (LDS_AS void*)l, 16, 0, 0);
}

// ---------------- workspace layout (bytes) ----------------
static constexpr size_t OFF_XB    = 0;                        // 16384*128*2
static constexpr size_t OFF_WCAT  = OFF_XB    + 4194304;      // 384*128*2
static constexpr size_t OFF_MQ    = OFF_WCAT  + 98304;        // 1024*128*2
static constexpr size_t OFF_MK    = OFF_MQ    + 262144;
static constexpr size_t OFF_BCAT  = OFF_MK    + 262144;       // 384*4 (pad)
static constexpr size_t OFF_BQF   = OFF_BCAT  + 2048;         // 1024*4
static constexpr size_t OFF_BKF   = OFF_BQF   + 4096;
static constexpr size_t OFF_Y     = OFF_BKF   + 4096;         // 16384*384*4
static constexpr size_t OFF_QF    = OFF_Y     + 25165824;     // 8*2048*1024*2
static constexpr size_t OFF_KF    = OFF_QF    + 33554432;
static constexpr size_t OFF_KFT   = OFF_KF    + 33554432;
static constexpr size_t OFF_VFT   = OFF_KFT   + 33554432;     // 8*128*2048*2
static constexpr size_t OFF_KPART = OFF_VFT   + 4194304;      // 8*128*4
static constexpr size_t OFF_KMAX  = OFF_KPART + 4096;         // 64*4
static constexpr size_t OFF_KSUM  = OFF_KMAX  + 256;          // 8*1024*4
static constexpr size_t OFF_DINV  = OFF_KSUM  + 32768;        // 16384*4
static constexpr size_t OFF_CTXP  = OFF_DINV  + 65536;        // 4*8*128*1024*4
static constexpr size_t OFF_CTXT  = OFF_CTXP  + 16777216;     // 8*128*1024*2
static constexpr size_t WS_NEED   = OFF_CTXT  + 2097152;      // ~147 MiB

// ---------------- shared NT-GEMM core: C(128x128) = A(tm:,*) * B(tn:,*)^T ----
static __device__ __forceinline__ void gemm_core(
    const __hip_bfloat16* __restrict__ A, const __hip_bfloat16* __restrict__ B,
    int lda, int ldb, int K, int tm, int tn,
    __bf16* As, __bf16* Bs, f32x4 acc[4][4]) {
  const int t    = threadIdx.x;
  const int w    = t >> 6;
  const int lane = t & 63;
  const int m_off = (w >> 1) << 6;
  const int n_off = (w & 1) << 6;
  const int r0 = t >> 2;            // 0..63 staging row
  const int kk = (t & 3) << 3;      // 0,8,16,24
  char* Asb = (char*)As + (w << 10);
  char* Bsb = (char*)Bs + (w << 10);
  const int frow = lane & 15;
  const int koff = (lane >> 4) << 3;
  for (int k0 = 0; k0 < K; k0 += 32) {
    const __hip_bfloat16* Ag = A + (size_t)(tm + r0) * lda + (k0 + kk);
    const __hip_bfloat16* Bg = B + (size_t)(tn + r0) * ldb + (k0 + kk);
    gload16(Ag, Asb);
    gload16(Ag + (size_t)64 * lda, Asb + 4096);
    gload16(Bg, Bsb);
    gload16(Bg + (size_t)64 * ldb, Bsb + 4096);
    __syncthreads();
    bf16x8 af[4], bfr[4];
#pragma unroll
    for (int mi = 0; mi < 4; ++mi)
      af[mi] = *(const bf16x8*)(As + ((m_off + mi * 16 + frow) << 5) + koff);
#pragma unroll
    for (int ni = 0; ni < 4; ++ni)
      bfr[ni] = *(const bf16x8*)(Bs + ((n_off + ni * 16 + frow) << 5) + koff);
#pragma unroll
    for (int mi = 0; mi < 4; ++mi)
#pragma unroll
      for (int ni = 0; ni < 4; ++ni)
        acc[mi][ni] = __builtin_amdgcn_mfma_f32_16x16x32_bf16(af[mi], bfr[ni], acc[mi][ni], 0, 0, 0);
    __syncthreads();
  }
}

#define ZERO_ACC(acc) do {                                   \
  _Pragma("unroll") for (int a_ = 0; a_ < 4; ++a_)           \
  _Pragma("unroll") for (int b_ = 0; b_ < 4; ++b_)           \
    acc[a_][b_] = (f32x4){0.f, 0.f, 0.f, 0.f};               \
} while (0)

// ---------------- prep kernels ----------------
__global__ void k_prepwb(const float* __restrict__ Wq, const float* __restrict__ bq,
                         const float* __restrict__ Wk, const float* __restrict__ bk,
                         const float* __restrict__ Wv, const float* __restrict__ bv,
                         __hip_bfloat16* __restrict__ Wcat, float* __restrict__ bcat) {
  int i = blockIdx.x * 256 + threadIdx.x;
  if (i < 49152) {
    int mat = i >> 14, rem = i & 16383;
    const float* W = (mat == 0) ? Wq : ((mat == 1) ? Wk : Wv);
    Wcat[i] = __float2bfloat16(W[rem]);
  }
  if (i < 384) {
    int mat = i >> 7;
    const float* b = (mat == 0) ? bq : ((mat == 1) ? bk : bv);
    bcat[i] = b[i & 127];
  }
}

__global__ void k_prepM(const float* __restrict__ Wq, const float* __restrict__ bq,
                        const float* __restrict__ Wk, const float* __restrict__ bk,
                        const float* __restrict__ proj,
                        __hip_bfloat16* __restrict__ Mq, __hip_bfloat16* __restrict__ Mk,
                        float* __restrict__ bqf, float* __restrict__ bkf) {
  int i = blockIdx.x * 256 + threadIdx.x;
  if (i < 262144) {
    int which = i >> 17;
    int rem = i & 131071;
    int hj = rem >> 7, e = rem & 127;
    int hh = hj >> 7, j = hj & 127;
    const float* W = which ? Wk : Wq;
    float s = 0.f;
#pragma unroll
    for (int u = 0; u < 16; ++u) s += proj[j * 16 + u] * W[(hh * 16 + u) * 128 + e];
    if (which) Mk[rem] = __float2bfloat16(0.5f * s);
    else       Mq[rem] = __float2bfloat16(0.5f * s);
  }
  if (i < 2048) {
    int which = i >> 10;
    int hj = i & 1023, hh = hj >> 7, j = hj & 127;
    const float* b = which ? bk : bq;
    float s = 0.f;
#pragma unroll
    for (int u = 0; u < 16; ++u) s += proj[j * 16 + u] * b[hh * 16 + u];
    if (which) bkf[hj] = 0.5f * s;
    else       bqf[hj] = 0.5f * s;
  }
}

__global__ void k_convx(const float* __restrict__ x, __hip_bfloat16* __restrict__ xb) {
  int i = (blockIdx.x * 256 + threadIdx.x) * 4;
  f32x4 v = *(const f32x4*)(x + i);
#pragma unroll
  for (int j = 0; j < 4; ++j) xb[i + j] = __float2bfloat16(v[j]);
}

// ---------------- projection GEMM: Y = x*Wcat^T + bcat ----------------
__global__ __launch_bounds__(256) void k_proj(
    const __hip_bfloat16* __restrict__ xb, const __hip_bfloat16* __restrict__ Wcat,
    const float* __restrict__ bcat, float* __restrict__ Y) {
  __shared__ __align__(16) __bf16 As[4096], Bs[4096];
  const int tm = blockIdx.x << 7, tn = blockIdx.y << 7;
  f32x4 acc[4][4];
  ZERO_ACC(acc);
  gemm_core(xb, Wcat, 128, 128, 128, tm, tn, As, Bs, acc);
  const int t = threadIdx.x, w = t >> 6, lane = t & 63;
  const int m_off = (w >> 1) << 6, n_off = (w & 1) << 6;
#pragma unroll
  for (int ni = 0; ni < 4; ++ni) {
    const int col = tn + n_off + ni * 16 + (lane & 15);
    const float bias = bcat[col];
#pragma unroll
    for (int mi = 0; mi < 4; ++mi)
#pragma unroll
      for (int i = 0; i < 4; ++i) {
        const int row = tm + m_off + mi * 16 + ((lane >> 4) << 2) + i;
        Y[(size_t)row * 384 + col] = acc[mi][ni][i] + bias;
      }
  }
}

// ---------------- vfT build (tiled transpose) ----------------
__global__ void k_vft2(const float* __restrict__ Y, __hip_bfloat16* __restrict__ vfT) {
  const int cb = blockIdx.x, r = blockIdx.y, h = blockIdx.z;
  const int c0 = cb << 7;
  __shared__ float tile[16][132];
  const int t = threadIdx.x;
  const int a = t & 15, cc0 = t >> 4;
#pragma unroll
  for (int i = 0; i < 8; ++i) {
    const int cc = cc0 + (i << 4);
    tile[a][cc] = Y[(size_t)(r * 2048 + c0 + cc) * 384 + 256 + (h << 4) + a];
  }
  __syncthreads();
  const int row = t >> 4, cg = t & 15;
  bf16x8 v;
#pragma unroll
  for (int j = 0; j < 8; ++j) v[j] = (__bf16)tile[row][(cg << 3) + j];
  *(bf16x8*)(vfT + ((size_t)((h << 7) + (r << 4) + row) << 11) + c0 + (cg << 3)) = v;
}

// ---------------- q features ----------------
__global__ __launch_bounds__(256) void k_dashq(
    const __hip_bfloat16* __restrict__ xb, const __hip_bfloat16* __restrict__ Mq,
    const float* __restrict__ bqf, const float* __restrict__ Y,
    __hip_bfloat16* __restrict__ qf) {
  __shared__ __align__(16) __bf16 As[4096], Bs[4096];
  __shared__ float diag_s[128];
  __shared__ float rmax_s[2][128];
  const int h = blockIdx.y;
  const int tm = blockIdx.x << 7;
  f32x4 acc[4][4];
  ZERO_ACC(acc);
  gemm_core(xb, Mq + h * 16384, 128, 128, 128, tm, 0, As, Bs, acc);
  const int t = threadIdx.x, w = t >> 6, lane = t & 63;
  const int m_off = (w >> 1) << 6, n_off = (w & 1) << 6;
  if (t < 128) {
    const float* yp = Y + (size_t)(tm + t) * 384 + h * 16;
    float s = 0.f;
#pragma unroll
    for (int u = 0; u < 16; ++u) s += yp[u] * yp[u];
    diag_s[t] = 0.125f * s;
  }
  float bia[4];
#pragma unroll
  for (int ni = 0; ni < 4; ++ni) bia[ni] = bqf[h * 128 + n_off + ni * 16 + (lane & 15)];
  float rmx[4][4];
#pragma unroll
  for (int mi = 0; mi < 4; ++mi)
#pragma unroll
    for (int i = 0; i < 4; ++i) {
      float m0 = acc[mi][0][i] + bia[0];
      m0 = fmaxf(m0, acc[mi][1][i] + bia[1]);
      m0 = fmaxf(m0, acc[mi][2][i] + bia[2]);
      m0 = fmaxf(m0, acc[mi][3][i] + bia[3]);
      rmx[mi][i] = m0;
    }
#pragma unroll
  for (int off = 1; off < 16; off <<= 1)
#pragma unroll
    for (int mi = 0; mi < 4; ++mi)
#pragma unroll
      for (int i = 0; i < 4; ++i)
        rmx[mi][i] = fmaxf(rmx[mi][i], __shfl_xor(rmx[mi][i], off));
  if ((lane & 15) == 0) {
#pragma unroll
    for (int mi = 0; mi < 4; ++mi)
#pragma unroll
      for (int i = 0; i < 4; ++i)
        rmax_s[w & 1][m_off + mi * 16 + ((lane >> 4) << 2) + i] = rmx[mi][i];
  }
  __syncthreads();
#pragma unroll
  for (int mi = 0; mi < 4; ++mi) {
#pragma unroll
    for (int i = 0; i < 4; ++i) {
      const int rl = m_off + mi * 16 + ((lane >> 4) << 2) + i;
      const int rg = tm + rl;
      const int c = rg & 2047, r = rg >> 11;
      const float md = diag_s[rl] + fmaxf(rmax_s[0][rl], rmax_s[1][rl]);
#pragma unroll
      for (int ni = 0; ni < 4; ++ni) {
        const int j = n_off + ni * 16 + (lane & 15);
        const float f = RATIO * (__expf(acc[mi][ni][i] + bia[ni] - md) + EPSV);
        qf[((size_t)((h << 11) + c) << 10) + (r << 7) + j] = __float2bfloat16(f);
      }
    }
  }
}

// ---------------- k features: pass A (max) ----------------
__global__ __launch_bounds__(256) void k_dashk_max(
    const __hip_bfloat16* __restrict__ xb, const __hip_bfloat16* __restrict__ Mk,
    const float* __restrict__ bkf, float* __restrict__ kpart) {
  __shared__ __align__(16) __bf16 As[4096], Bs[4096];
  __shared__ float wmax[4];
  const int h = blockIdx.y;
  const int tm = blockIdx.x << 7;
  f32x4 acc[4][4];
  ZERO_ACC(acc);
  gemm_core(xb, Mk + h * 16384, 128, 128, 128, tm, 0, As, Bs, acc);
  const int t = threadIdx.x, w = t >> 6, lane = t & 63;
  const int n_off = (w & 1) << 6;
  float mx = -1e30f;
#pragma unroll
  for (int ni = 0; ni < 4; ++ni) {
    const float bia = bkf[h * 128 + n_off + ni * 16 + (lane & 15)];
#pragma unroll
    for (int mi = 0; mi < 4; ++mi)
#pragma unroll
      for (int i = 0; i < 4; ++i) mx = fmaxf(mx, acc[mi][ni][i] + bia);
  }
#pragma unroll
  for (int off = 1; off < 64; off <<= 1) mx = fmaxf(mx, __shfl_xor(mx, off));
  if (lane == 0) wmax[w] = mx;
  __syncthreads();
  if (t == 0) kpart[h * 128 + blockIdx.x] = fmaxf(fmaxf(wmax[0], wmax[1]), fmaxf(wmax[2], wmax[3]));
}

__global__ void k_kmaxred(const float* __restrict__ kpart, float* __restrict__ kmax) {
  const int t = threadIdx.x;  // 64
  const int r = t >> 3, h = t & 7;
  float m = -1e30f;
  for (int i = 0; i < 16; ++i) m = fmaxf(m, kpart[h * 128 + r * 16 + i]);
  kmax[r * 8 + h] = m;
}

// ---------------- k features: pass B (features, kf + kfT) ----------------
__global__ __launch_bounds__(256) void k_dashk_feat(
    const __hip_bfloat16* __restrict__ xb, const __hip_bfloat16* __restrict__ Mk,
    const float* __restrict__ bkf, const float* __restrict__ Y,
    const float* __restrict__ kmax,
    __hip_bfloat16* __restrict__ kf, __hip_bfloat16* __restrict__ kfT) {
  __shared__ __align__(16) __bf16 As[4096], Bs[4096];
  __shared__ float diag_s[128];
  __shared__ __align__(16) __bf16 kT[128 * 136];
  const int h = blockIdx.y;
  const int tm = blockIdx.x << 7;
  f32x4 acc[4][4];
  ZERO_ACC(acc);
  gemm_core(xb, Mk + h * 16384, 128, 128, 128, tm, 0, As, Bs, acc);
  const int t = threadIdx.x, w = t >> 6, lane = t & 63;
  const int m_off = (w >> 1) << 6, n_off = (w & 1) << 6;
  if (t < 128) {
    const float* yp = Y + (size_t)(tm + t) * 384 + 128 + h * 16;
    float s = 0.f;
#pragma unroll
    for (int u = 0; u < 16; ++u) s += yp[u] * yp[u];
    diag_s[t] = 0.125f * s;
  }
  const int r = tm >> 11;
  const int c0 = tm & 2047;
  const float m = kmax[r * 8 + h];
  float bia[4];
#pragma unroll
  for (int ni = 0; ni < 4; ++ni) bia[ni] = bkf[h * 128 + n_off + ni * 16 + (lane & 15)];
  __syncthreads();
#pragma unroll
  for (int mi = 0; mi < 4; ++mi) {
#pragma unroll
    for (int i = 0; i < 4; ++i) {
      const int rl = m_off + mi * 16 + ((lane >> 4) << 2) + i;
      const int c = c0 + rl;
      const float dm = diag_s[rl] + m;
#pragma unroll
      for (int ni = 0; ni < 4; ++ni) {
        const int j = n_off + ni * 16 + (lane & 15);
        const float f = RATIO * (__expf(acc[mi][ni][i] + bia[ni] - dm) + EPSV);
        kf[((size_t)((h << 11) + c) << 10) + (r << 7) + j] = __float2bfloat16(f);
        kT[j * 136 + rl] = (__bf16)f;
      }
    }
  }
  __syncthreads();
  const int j2 = t >> 1, half = t & 1;
  __bf16* dst = (__bf16*)kfT + (((size_t)(h << 10) + (r << 7) + j2) << 11) + c0 + (half << 6);
  const __bf16* srcr = kT + j2 * 136 + (half << 6);
#pragma unroll
  for (int q8 = 0; q8 < 8; ++q8)
    *(bf16x8*)(dst + (q8 << 3)) = *(const bf16x8*)(srcr + (q8 << 3));
}

// ---------------- k_sum (row-reduce over kfT, coalesced) ----------------
__global__ __launch_bounds__(256) void k_ksum2(const __hip_bfloat16* __restrict__ kfT,
                                               float* __restrict__ ksum) {
  const int t = threadIdx.x, w = t >> 6, lane = t & 63;
  const int row = blockIdx.x * 4 + w;            // 0..8191 = h*1024 + d
  const __bf16* p = (const __bf16*)kfT + ((size_t)row << 11);
  float s = 0.f;
#pragma unroll
  for (int q = 0; q < 4; ++q) {
    bf16x8 v = *(const bf16x8*)(p + ((lane + (q << 6)) << 3));
#pragma unroll
    for (int j = 0; j < 8; ++j) s += (float)v[j];
  }
#pragma unroll
  for (int off = 1; off < 64; off <<= 1) s += __shfl_xor(s, off);
  if (lane == 0) ksum[row] = s;
}

__global__ __launch_bounds__(256) void k_dinv(
    const __hip_bfloat16* __restrict__ qf, const float* __restrict__ ksum,
    float* __restrict__ dinv) {
  const int t = threadIdx.x, w = t >> 6, lane = t & 63;
  const int h = blockIdx.y;
  const int c = blockIdx.x * 4 + w;
  const __bf16* qp = (const __bf16*)qf + ((size_t)((h << 11) + c) << 10);
  const float* ks = ksum + h * 1024;
  const int d0 = lane << 4;
  bf16x8 v0 = *(const bf16x8*)(qp + d0);
  bf16x8 v1 = *(const bf16x8*)(qp + d0 + 8);
  float s = 0.f;
#pragma unroll
  for (int j = 0; j < 8; ++j) s += (float)v0[j] * ks[d0 + j] + (float)v1[j] * ks[d0 + 8 + j];
#pragma unroll
  for (int off = 1; off < 64; off <<= 1) s += __shfl_xor(s, off);
  if (lane == 0) dinv[(h << 11) + c] = 1.0f / s;
}

// ---------------- attn GEMM: 256x256 tile, 2-phase counted-vmcnt pipeline ----
#define SBAR() __builtin_amdgcn_s_barrier()
#define FEN()  do { asm volatile("" ::: "memory"); __builtin_amdgcn_sched_barrier(0); } while (0)
#define PRIO1() __builtin_amdgcn_s_setprio(1)
#define PRIO0() __builtin_amdgcn_s_setprio(0)

// stage one 128x32 half-tile (1 gload16/thread), linear LDS dest,
// inverse-swizzled global source (T2 both-sides rule).
static __device__ __forceinline__ void stage_half(
    const __hip_bfloat16* __restrict__ G, int row0, int k0, char* ldstile, int half) {
  const int t = threadIdx.x;
  const int wid = t >> 6;
  const int sr = t >> 2;                                    // 0..127
  const int scol = (((t & 3) ^ ((t >> 3) & 3)) << 3);       // swizzle-inverse col
  gload16(G + (size_t)(row0 + half * 128 + sr) * 1024 + (k0 + scol),
          ldstile + half * 8192 + (wid << 10));
}

#define LDA4(dst, buf, qm) do {                                              \
  _Pragma("unroll") for (int mi_ = 0; mi_ < 4; ++mi_)                        \
    dst[mi_] = *(const bf16x8*)((buf) + (qm) * 8192 + mi_ * 1024 + abase);   \
} while (0)
#define LDB2(dst, buf, qn) do {                                              \
  _Pragma("unroll") for (int ni_ = 0; ni_ < 2; ++ni_)                        \
    dst[ni_] = *(const bf16x8*)((buf) + (qn) * 8192 + ni_ * 1024 + bbase);   \
} while (0)
#define MFMA8(ACC, AR, BR) do {                                              \
  _Pragma("unroll") for (int mi_ = 0; mi_ < 4; ++mi_)                        \
  _Pragma("unroll") for (int ni_ = 0; ni_ < 2; ++ni_)                        \
    ACC[mi_][ni_] = __builtin_amdgcn_mfma_f32_16x16x32_bf16(                 \
        AR[mi_], BR[ni_], ACC[mi_][ni_], 0, 0, 0);                           \
} while (0)

__global__ __launch_bounds__(512, 2) void k_attn8(
    const __hip_bfloat16* __restrict__ qf, const __hip_bfloat16* __restrict__ kf,
    float* __restrict__ attn) {
  __shared__ __align__(64) char lds[65536];  // A:[2][256][32]bf16 @0, B @32768
  // bijective XCD swizzle: 512 blocks, 64/XCD -> one head per XCD
  const int lid = ((blockIdx.z << 3) + blockIdx.y) * 8 + blockIdx.x;
  const int swz = ((lid & 7) << 6) + (lid >> 3);
  const int h  = swz >> 6;
  const int tm = (((swz >> 3) & 7) << 8);
  const int tn = ((swz & 7) << 8);
  const __hip_bfloat16* Ag = qf + ((size_t)h << 21);
  const __hip_bfloat16* Bg = kf + ((size_t)h << 21);

  const int t = threadIdx.x, wid = t >> 6, lane = t & 63;
  const int f = lane & 15;
  const int wr = wid >> 2, wc = wid & 3;
  const int colpart = (((lane >> 4) ^ ((lane >> 1) & 3)) << 4);  // T2 read swizzle
  const int abase = (wr * 64 + f) * 64 + colpart;
  const int bbase = (wc * 32 + f) * 64 + colpart;

  f32x4 acc00[4][2] = {}, acc01[4][2] = {}, acc10[4][2] = {}, acc11[4][2] = {};
  bf16x8 aR[4], bq0[2], bq1[2];

  // prologue: stage tile 0 into buf0 in order [Ah0,Bh0,Bh1,Ah1]
  stage_half(Ag, tm, 0, lds, 0);
  stage_half(Bg, tn, 0, lds + 32768, 0);
  stage_half(Bg, tn, 0, lds + 32768, 1);
  stage_half(Ag, tm, 0, lds, 1);
  asm volatile("s_waitcnt vmcnt(1)" ::: "memory");
  SBAR(); FEN();

  for (int kt = 0; kt < 31; ++kt) {
    const int b = kt & 1;
    char* Ab = lds + b * 16384;
    char* Bb = lds + 32768 + b * 16384;
    char* An = lds + (b ^ 1) * 16384;
    char* Bn = lds + 32768 + (b ^ 1) * 16384;
    const int nk0 = (kt + 1) << 5;
    // P1: quadrants (qm0,qn0)+(qm0,qn1); prefetch Ah0,Bh0 of t+1
    LDA4(aR, Ab, 0); LDB2(bq0, Bb, 0); LDB2(bq1, Bb, 1);
    stage_half(Ag, tm, nk0, An, 0);
    stage_half(Bg, tn, nk0, Bn, 0);
    SBAR(); FEN();
    PRIO1(); MFMA8(acc00, aR, bq0); MFMA8(acc01, aR, bq1); PRIO0();
    asm volatile("s_waitcnt vmcnt(2)" ::: "memory");
    SBAR(); FEN();
    // P2: quadrants (qm1,qn0)+(qm1,qn1); prefetch Bh1,Ah1 of t+1
    LDA4(aR, Ab, 1);
    stage_half(Bg, tn, nk0, Bn, 1);
    stage_half(Ag, tm, nk0, An, 1);
    SBAR(); FEN();
    PRIO1(); MFMA8(acc10, aR, bq0); MFMA8(acc11, aR, bq1); PRIO0();
    asm volatile("s_waitcnt vmcnt(1)" ::: "memory");
    SBAR(); FEN();
  }
  { // epilogue tile 31 (buf1), drain
    char* Ab = lds + 16384;
    char* Bb = lds + 32768 + 16384;
    LDA4(aR, Ab, 0); LDB2(bq0, Bb, 0); LDB2(bq1, Bb, 1);
    PRIO1(); MFMA8(acc00, aR, bq0); MFMA8(acc01, aR, bq1); PRIO0();
    asm volatile("s_waitcnt vmcnt(0)" ::: "memory");
    SBAR(); FEN();
    LDA4(aR, Ab, 1);
    PRIO1(); MFMA8(acc10, aR, bq0); MFMA8(acc11, aR, bq1); PRIO0();
  }

  float* Cc = attn + ((size_t)h << 22);
  const int rbase = tm + wr * 64 + ((lane >> 4) << 2);
  const int cbase = tn + wc * 32 + f;
#pragma unroll
  for (int mi = 0; mi < 4; ++mi)
#pragma unroll
    for (int i = 0; i < 4; ++i) {
      float* r0 = Cc + ((size_t)(rbase + mi * 16 + i) << 11) + cbase;
      float* r1 = Cc + ((size_t)(rbase + 128 + mi * 16 + i) << 11) + cbase;
#pragma unroll
      for (int ni = 0; ni < 2; ++ni) {
        r0[ni * 16]       = acc00[mi][ni][i];
        r0[128 + ni * 16] = acc01[mi][ni][i];
        r1[ni * 16]       = acc10[mi][ni][i];
        r1[128 + ni * 16] = acc11[mi][ni][i];
      }
    }
}

// ---------------- context GEMM (K-split) ----------------
__global__ __launch_bounds__(256) void k_ctx(
    const __hip_bfloat16* __restrict__ vfT, const __hip_bfloat16* __restrict__ kfT,
    float* __restrict__ ctxp) {
  __shared__ __align__(16) __bf16 As[4096], Bs[4096];
  const int z = blockIdx.z, h = z >> 2, kc = z & 3;
  const int tn = blockIdx.y << 7;
  f32x4 acc[4][4];
  ZERO_ACC(acc);
  gemm_core(vfT + ((size_t)h << 18) + (kc << 9), kfT + ((size_t)h << 21) + (kc << 9),
            2048, 2048, 512, 0, tn, As, Bs, acc);
  float* Cp = ctxp + ((size_t)(kc * 8 + h) << 17);
  const int t = threadIdx.x, w = t >> 6, lane = t & 63;
  const int m_off = (w >> 1) << 6, n_off = (w & 1) << 6;
#pragma unroll
  for (int mi = 0; mi < 4; ++mi)
#pragma unroll
    for (int i = 0; i < 4; ++i) {
      const int row = m_off + mi * 16 + ((lane >> 4) << 2) + i;
#pragma unroll
      for (int ni = 0; ni < 4; ++ni) {
        const int col = tn + n_off + ni * 16 + (lane & 15);
        Cp[((size_t)row << 10) + col] = acc[mi][ni][i];
      }
    }
}

__global__ void k_ctxred(const float* __restrict__ ctxp, __hip_bfloat16* __restrict__ ctxT) {
  const int i = blockIdx.x * 256 + threadIdx.x;
  const float s = ctxp[i] + ctxp[i + 1048576] + ctxp[i + 2097152] + ctxp[i + 3145728];
  ctxT[i] = __float2bfloat16(s);
}

// ---------------- out GEMM + D_inv scale + scatter ----------------
__global__ __launch_bounds__(256) void k_out(
    const __hip_bfloat16* __restrict__ qf, const __hip_bfloat16* __restrict__ ctxT,
    const float* __restrict__ dinv, float* __restrict__ outp) {
  __shared__ __align__(16) __bf16 As[4096], Bs[4096];
  const int h = blockIdx.z;
  const int tm = blockIdx.x << 7;
  f32x4 acc[4][4];
  ZERO_ACC(acc);
  gemm_core(qf + ((size_t)h << 21), ctxT + ((size_t)h << 17), 1024, 1024, 1024, tm, 0, As, Bs, acc);
  const int t = threadIdx.x, w = t >> 6, lane = t & 63;
  const int m_off = (w >> 1) << 6, n_off = (w & 1) << 6;
#pragma unroll
  for (int mi = 0; mi < 4; ++mi)
#pragma unroll
    for (int i = 0; i < 4; ++i) {
      const int row = tm + m_off + mi * 16 + ((lane >> 4) << 2) + i;
      const float dv = dinv[(h << 11) + row];
#pragma unroll
      for (int ni = 0; ni < 4; ++ni) {
        const int col = n_off + ni * 16 + (lane & 15);
        const int rb = col >> 4, tt = col & 15;
        outp[(((size_t)(rb << 11) + row) << 7) + (h << 4) + tt] = acc[mi][ni][i] * dv;
      }
    }
}

// ---------------- launch ----------------
extern "C" void kernel_launch(void* const* d_in, const int* in_sizes, int n_in,
                              void* d_out, int out_size, void* d_ws, size_t ws_size,
                              hipStream_t stream) {
  const float* x    = (const float*)d_in[0];
  const float* Wq   = (const float*)d_in[1];
  const float* bq   = (const float*)d_in[2];
  const float* Wk   = (const float*)d_in[3];
  const float* bk   = (const float*)d_in[4];
  const float* Wv   = (const float*)d_in[5];
  const float* bv   = (const float*)d_in[6];
  const float* proj = (const float*)d_in[7];
  if (ws_size < WS_NEED) return;

  char* ws = (char*)d_ws;
  __hip_bfloat16* xb   = (__hip_bfloat16*)(ws + OFF_XB);
  __hip_bfloat16* Wcat = (__hip_bfloat16*)(ws + OFF_WCAT);
  __hip_bfloat16* Mq   = (__hip_bfloat16*)(ws + OFF_MQ);
  __hip_bfloat16* Mk   = (__hip_bfloat16*)(ws + OFF_MK);
  float* bcat = (float*)(ws + OFF_BCAT);
  float* bqf  = (float*)(ws + OFF_BQF);
  float* bkf  = (float*)(ws + OFF_BKF);
  float* Y    = (float*)(ws + OFF_Y);
  __hip_bfloat16* qf  = (__hip_bfloat16*)(ws + OFF_QF);
  __hip_bfloat16* kf  = (__hip_bfloat16*)(ws + OFF_KF);
  __hip_bfloat16* kfT = (__hip_bfloat16*)(ws + OFF_KFT);
  __hip_bfloat16* vfT = (__hip_bfloat16*)(ws + OFF_VFT);
  float* kpart = (float*)(ws + OFF_KPART);
  float* kmax  = (float*)(ws + OFF_KMAX);
  float* ksum  = (float*)(ws + OFF_KSUM);
  float* dinv  = (float*)(ws + OFF_DINV);
  float* ctxp  = (float*)(ws + OFF_CTXP);
  __hip_bfloat16* ctxT = (__hip_bfloat16*)(ws + OFF_CTXT);

  float* outp = (float*)d_out;
  float* attn = (float*)d_out + 2097152;

  k_prepwb<<<dim3(192), dim3(256), 0, stream>>>(Wq, bq, Wk, bk, Wv, bv, Wcat, bcat);
  k_prepM<<<dim3(1024), dim3(256), 0, stream>>>(Wq, bq, Wk, bk, proj, Mq, Mk, bqf, bkf);
  k_convx<<<dim3(2048), dim3(256), 0, stream>>>(x, xb);
  k_proj<<<dim3(128, 3), dim3(256), 0, stream>>>(xb, Wcat, bcat, Y);
  k_vft2<<<dim3(16, 8, 8), dim3(256), 0, stream>>>(Y, vfT);
  k_dashq<<<dim3(128, 8), dim3(256), 0, stream>>>(xb, Mq, bqf, Y, qf);
  k_dashk_max<<<dim3(128, 8), dim3(256), 0, stream>>>(xb, Mk, bkf, kpart);
  k_kmaxred<<<dim3(1), dim3(64), 0, stream>>>(kpart, kmax);
  k_dashk_feat<<<dim3(128, 8), dim3(256), 0, stream>>>(xb, Mk, bkf, Y, kmax, kf, kfT);
  k_ksum2<<<dim3(2048), dim3(256), 0, stream>>>(kfT, ksum);
  k_dinv<<<dim3(512, 8), dim3(256), 0, stream>>>(qf, ksum, dinv);
  k_attn8<<<dim3(8, 8, 8), dim3(512), 0, stream>>>(qf, kf, attn);
  k_ctx<<<dim3(1, 8, 32), dim3(256), 0, stream>>>(vfT, kfT, ctxp);
  k_ctxred<<<dim3(4096), dim3(256), 0, stream>>>(ctxp, ctxT);
  k_out<<<dim3(16, 1, 8), dim3(256), 0, stream>>>(qf, ctxT, dinv, outp);
}

// Round 4
// 201.506 us; speedup vs baseline: 3.5294x; 1.0668x over previous
//
#include <hip/hip_runtime.h>
#include <hip/hip_bf16.h>
#include <stdint.h>

typedef __bf16 bf16x8 __attribute__((ext_vector_type(8)));
typedef float  f32x4  __attribute__((ext_vector_type(4)));

#define RATIO 0.08838834764831845f
#define EPSV  1e-4f

#define GLOBAL_AS __attribute__((address_space(1)))
#define LDS_AS    __attribute__((address_space(3)))

static __device__ __forceinline__ void gload16(const void* g, void* l) {
  __builtin_amdgcn_global_load_lds((GLOBAL_AS const void*)g, (LDS_AS void*)l, 16, 0, 0);
}

// ---------------- workspace layout (bytes) ----------------
static constexpr size_t OFF_XB    = 0;                        // 16384*128*2
static constexpr size_t OFF_WCAT  = OFF_XB    + 4194304;      // 384*128*2
static constexpr size_t OFF_MQ    = OFF_WCAT  + 98304;        // 1024*128*2
static constexpr size_t OFF_MK    = OFF_MQ    + 262144;
static constexpr size_t OFF_BCAT  = OFF_MK    + 262144;       // 384*4 (pad)
static constexpr size_t OFF_BQF   = OFF_BCAT  + 2048;         // 1024*4
static constexpr size_t OFF_BKF   = OFF_BQF   + 4096;
static constexpr size_t OFF_Y     = OFF_BKF   + 4096;         // 16384*384*4
static constexpr size_t OFF_QF    = OFF_Y     + 25165824;     // 8*2048*1024*2
static constexpr size_t OFF_KF    = OFF_QF    + 33554432;
static constexpr size_t OFF_KFT   = OFF_KF    + 33554432;
static constexpr size_t OFF_VFT   = OFF_KFT   + 33554432;     // 8*128*2048*2
static constexpr size_t OFF_KPART = OFF_VFT   + 4194304;      // 8*128*4
static constexpr size_t OFF_KMAX  = OFF_KPART + 4096;         // 64*4
static constexpr size_t OFF_KSUM  = OFF_KMAX  + 256;          // 8*1024*4
static constexpr size_t OFF_DINV  = OFF_KSUM  + 32768;        // 16384*4
static constexpr size_t OFF_CTXP  = OFF_DINV  + 65536;        // 4*8*128*1024*4
static constexpr size_t OFF_CTXT  = OFF_CTXP  + 16777216;     // 8*128*1024*2
static constexpr size_t WS_NEED   = OFF_CTXT  + 2097152;      // ~147 MiB

// ---------------- shared NT-GEMM core: C(128x128) = A(tm:,*) * B(tn:,*)^T ----
static __device__ __forceinline__ void gemm_core(
    const __hip_bfloat16* __restrict__ A, const __hip_bfloat16* __restrict__ B,
    int lda, int ldb, int K, int tm, int tn,
    __bf16* As, __bf16* Bs, f32x4 acc[4][4]) {
  const int t    = threadIdx.x;
  const int w    = t >> 6;
  const int lane = t & 63;
  const int m_off = (w >> 1) << 6;
  const int n_off = (w & 1) << 6;
  const int r0 = t >> 2;            // 0..63 staging row
  const int kk = (t & 3) << 3;      // 0,8,16,24
  char* Asb = (char*)As + (w << 10);
  char* Bsb = (char*)Bs + (w << 10);
  const int frow = lane & 15;
  const int koff = (lane >> 4) << 3;
  for (int k0 = 0; k0 < K; k0 += 32) {
    const __hip_bfloat16* Ag = A + (size_t)(tm + r0) * lda + (k0 + kk);
    const __hip_bfloat16* Bg = B + (size_t)(tn + r0) * ldb + (k0 + kk);
    gload16(Ag, Asb);
    gload16(Ag + (size_t)64 * lda, Asb + 4096);
    gload16(Bg, Bsb);
    gload16(Bg + (size_t)64 * ldb, Bsb + 4096);
    __syncthreads();
    bf16x8 af[4], bfr[4];
#pragma unroll
    for (int mi = 0; mi < 4; ++mi)
      af[mi] = *(const bf16x8*)(As + ((m_off + mi * 16 + frow) << 5) + koff);
#pragma unroll
    for (int ni = 0; ni < 4; ++ni)
      bfr[ni] = *(const bf16x8*)(Bs + ((n_off + ni * 16 + frow) << 5) + koff);
#pragma unroll
    for (int mi = 0; mi < 4; ++mi)
#pragma unroll
      for (int ni = 0; ni < 4; ++ni)
        acc[mi][ni] = __builtin_amdgcn_mfma_f32_16x16x32_bf16(af[mi], bfr[ni], acc[mi][ni], 0, 0, 0);
    __syncthreads();
  }
}

#define ZERO_ACC(acc) do {                                   \
  _Pragma("unroll") for (int a_ = 0; a_ < 4; ++a_)           \
  _Pragma("unroll") for (int b_ = 0; b_ < 4; ++b_)           \
    acc[a_][b_] = (f32x4){0.f, 0.f, 0.f, 0.f};               \
} while (0)

// ---------------- fused prep kernel ----------------
__global__ void k_prep(const float* __restrict__ x,
                       const float* __restrict__ Wq, const float* __restrict__ bq,
                       const float* __restrict__ Wk, const float* __restrict__ bk,
                       const float* __restrict__ Wv, const float* __restrict__ bv,
                       const float* __restrict__ proj,
                       __hip_bfloat16* __restrict__ xb,
                       __hip_bfloat16* __restrict__ Wcat, float* __restrict__ bcat,
                       __hip_bfloat16* __restrict__ Mq, __hip_bfloat16* __restrict__ Mk,
                       float* __restrict__ bqf, float* __restrict__ bkf) {
  const int b = blockIdx.x, t = threadIdx.x;
  { // convx: all 2048 blocks
    int i = (b * 256 + t) * 4;
    f32x4 v = *(const f32x4*)(x + i);
#pragma unroll
    for (int j = 0; j < 4; ++j) xb[i + j] = __float2bfloat16(v[j]);
  }
  if (b < 1024) { // prepM
    int i = b * 256 + t;
    {
      int which = i >> 17;
      int rem = i & 131071;
      int hj = rem >> 7, e = rem & 127;
      int hh = hj >> 7, j = hj & 127;
      const float* W = which ? Wk : Wq;
      float s = 0.f;
#pragma unroll
      for (int u = 0; u < 16; ++u) s += proj[j * 16 + u] * W[(hh * 16 + u) * 128 + e];
      if (which) Mk[rem] = __float2bfloat16(0.5f * s);
      else       Mq[rem] = __float2bfloat16(0.5f * s);
    }
    if (i < 2048) {
      int which = i >> 10;
      int hj = i & 1023, hh = hj >> 7, j = hj & 127;
      const float* bb = which ? bk : bq;
      float s = 0.f;
#pragma unroll
      for (int u = 0; u < 16; ++u) s += proj[j * 16 + u] * bb[hh * 16 + u];
      if (which) bkf[hj] = 0.5f * s;
      else       bqf[hj] = 0.5f * s;
    }
  }
  if (b < 192) { // prepwb
    int i = b * 256 + t;
    int mat = i >> 14, rem = i & 16383;
    const float* W = (mat == 0) ? Wq : ((mat == 1) ? Wk : Wv);
    Wcat[i] = __float2bfloat16(W[rem]);
    if (i < 384) {
      int m2 = i >> 7;
      const float* bb = (m2 == 0) ? bq : ((m2 == 1) ? bk : bv);
      bcat[i] = bb[i & 127];
    }
  }
}

// ---------------- projection GEMM: Y = x*Wcat^T + bcat ----------------
__global__ __launch_bounds__(256) void k_proj(
    const __hip_bfloat16* __restrict__ xb, const __hip_bfloat16* __restrict__ Wcat,
    const float* __restrict__ bcat, float* __restrict__ Y) {
  __shared__ __align__(16) __bf16 As[4096], Bs[4096];
  const int tm = blockIdx.x << 7, tn = blockIdx.y << 7;
  f32x4 acc[4][4];
  ZERO_ACC(acc);
  gemm_core(xb, Wcat, 128, 128, 128, tm, tn, As, Bs, acc);
  const int t = threadIdx.x, w = t >> 6, lane = t & 63;
  const int m_off = (w >> 1) << 6, n_off = (w & 1) << 6;
#pragma unroll
  for (int ni = 0; ni < 4; ++ni) {
    const int col = tn + n_off + ni * 16 + (lane & 15);
    const float bias = bcat[col];
#pragma unroll
    for (int mi = 0; mi < 4; ++mi)
#pragma unroll
      for (int i = 0; i < 4; ++i) {
        const int row = tm + m_off + mi * 16 + ((lane >> 4) << 2) + i;
        Y[(size_t)row * 384 + col] = acc[mi][ni][i] + bias;
      }
  }
}

// ---------------- vfT build (tiled transpose) ----------------
__global__ void k_vft2(const float* __restrict__ Y, __hip_bfloat16* __restrict__ vfT) {
  const int cb = blockIdx.x, r = blockIdx.y, h = blockIdx.z;
  const int c0 = cb << 7;
  __shared__ float tile[16][132];
  const int t = threadIdx.x;
  const int a = t & 15, cc0 = t >> 4;
#pragma unroll
  for (int i = 0; i < 8; ++i) {
    const int cc = cc0 + (i << 4);
    tile[a][cc] = Y[(size_t)(r * 2048 + c0 + cc) * 384 + 256 + (h << 4) + a];
  }
  __syncthreads();
  const int row = t >> 4, cg = t & 15;
  bf16x8 v;
#pragma unroll
  for (int j = 0; j < 8; ++j) v[j] = (__bf16)tile[row][(cg << 3) + j];
  *(bf16x8*)(vfT + ((size_t)((h << 7) + (r << 4) + row) << 11) + c0 + (cg << 3)) = v;
}

// ---------------- q features ----------------
__global__ __launch_bounds__(256) void k_dashq(
    const __hip_bfloat16* __restrict__ xb, const __hip_bfloat16* __restrict__ Mq,
    const float* __restrict__ bqf, const float* __restrict__ Y,
    __hip_bfloat16* __restrict__ qf) {
  __shared__ __align__(16) __bf16 As[4096], Bs[4096];
  __shared__ float diag_s[128];
  __shared__ float rmax_s[2][128];
  const int h = blockIdx.y;
  const int tm = blockIdx.x << 7;
  f32x4 acc[4][4];
  ZERO_ACC(acc);
  gemm_core(xb, Mq + h * 16384, 128, 128, 128, tm, 0, As, Bs, acc);
  const int t = threadIdx.x, w = t >> 6, lane = t & 63;
  const int m_off = (w >> 1) << 6, n_off = (w & 1) << 6;
  if (t < 128) {
    const float* yp = Y + (size_t)(tm + t) * 384 + h * 16;
    float s = 0.f;
#pragma unroll
    for (int u = 0; u < 16; ++u) s += yp[u] * yp[u];
    diag_s[t] = 0.125f * s;
  }
  float bia[4];
#pragma unroll
  for (int ni = 0; ni < 4; ++ni) bia[ni] = bqf[h * 128 + n_off + ni * 16 + (lane & 15)];
  float rmx[4][4];
#pragma unroll
  for (int mi = 0; mi < 4; ++mi)
#pragma unroll
    for (int i = 0; i < 4; ++i) {
      float m0 = acc[mi][0][i] + bia[0];
      m0 = fmaxf(m0, acc[mi][1][i] + bia[1]);
      m0 = fmaxf(m0, acc[mi][2][i] + bia[2]);
      m0 = fmaxf(m0, acc[mi][3][i] + bia[3]);
      rmx[mi][i] = m0;
    }
#pragma unroll
  for (int off = 1; off < 16; off <<= 1)
#pragma unroll
    for (int mi = 0; mi < 4; ++mi)
#pragma unroll
      for (int i = 0; i < 4; ++i)
        rmx[mi][i] = fmaxf(rmx[mi][i], __shfl_xor(rmx[mi][i], off));
  if ((lane & 15) == 0) {
#pragma unroll
    for (int mi = 0; mi < 4; ++mi)
#pragma unroll
      for (int i = 0; i < 4; ++i)
        rmax_s[w & 1][m_off + mi * 16 + ((lane >> 4) << 2) + i] = rmx[mi][i];
  }
  __syncthreads();
#pragma unroll
  for (int mi = 0; mi < 4; ++mi) {
#pragma unroll
    for (int i = 0; i < 4; ++i) {
      const int rl = m_off + mi * 16 + ((lane >> 4) << 2) + i;
      const int rg = tm + rl;
      const int c = rg & 2047, r = rg >> 11;
      const float md = diag_s[rl] + fmaxf(rmax_s[0][rl], rmax_s[1][rl]);
#pragma unroll
      for (int ni = 0; ni < 4; ++ni) {
        const int j = n_off + ni * 16 + (lane & 15);
        const float f = RATIO * (__expf(acc[mi][ni][i] + bia[ni] - md) + EPSV);
        qf[((size_t)((h << 11) + c) << 10) + (r << 7) + j] = __float2bfloat16(f);
      }
    }
  }
}

// ---------------- k features: pass A (max) ----------------
__global__ __launch_bounds__(256) void k_dashk_max(
    const __hip_bfloat16* __restrict__ xb, const __hip_bfloat16* __restrict__ Mk,
    const float* __restrict__ bkf, float* __restrict__ kpart) {
  __shared__ __align__(16) __bf16 As[4096], Bs[4096];
  __shared__ float wmax[4];
  const int h = blockIdx.y;
  const int tm = blockIdx.x << 7;
  f32x4 acc[4][4];
  ZERO_ACC(acc);
  gemm_core(xb, Mk + h * 16384, 128, 128, 128, tm, 0, As, Bs, acc);
  const int t = threadIdx.x, w = t >> 6, lane = t & 63;
  const int n_off = (w & 1) << 6;
  float mx = -1e30f;
#pragma unroll
  for (int ni = 0; ni < 4; ++ni) {
    const float bia = bkf[h * 128 + n_off + ni * 16 + (lane & 15)];
#pragma unroll
    for (int mi = 0; mi < 4; ++mi)
#pragma unroll
      for (int i = 0; i < 4; ++i) mx = fmaxf(mx, acc[mi][ni][i] + bia);
  }
#pragma unroll
  for (int off = 1; off < 64; off <<= 1) mx = fmaxf(mx, __shfl_xor(mx, off));
  if (lane == 0) wmax[w] = mx;
  __syncthreads();
  if (t == 0) kpart[h * 128 + blockIdx.x] = fmaxf(fmaxf(wmax[0], wmax[1]), fmaxf(wmax[2], wmax[3]));
}

__global__ void k_kmaxred(const float* __restrict__ kpart, float* __restrict__ kmax) {
  const int t = threadIdx.x;  // 64
  const int r = t >> 3, h = t & 7;
  float m = -1e30f;
  for (int i = 0; i < 16; ++i) m = fmaxf(m, kpart[h * 128 + r * 16 + i]);
  kmax[r * 8 + h] = m;
}

// ---------------- k features: pass B (features, kf + kfT) ----------------
__global__ __launch_bounds__(256) void k_dashk_feat(
    const __hip_bfloat16* __restrict__ xb, const __hip_bfloat16* __restrict__ Mk,
    const float* __restrict__ bkf, const float* __restrict__ Y,
    const float* __restrict__ kmax,
    __hip_bfloat16* __restrict__ kf, __hip_bfloat16* __restrict__ kfT) {
  __shared__ __align__(16) __bf16 As[4096], Bs[4096];
  __shared__ float diag_s[128];
  __shared__ __align__(16) __bf16 kT[128 * 136];
  const int h = blockIdx.y;
  const int tm = blockIdx.x << 7;
  f32x4 acc[4][4];
  ZERO_ACC(acc);
  gemm_core(xb, Mk + h * 16384, 128, 128, 128, tm, 0, As, Bs, acc);
  const int t = threadIdx.x, w = t >> 6, lane = t & 63;
  const int m_off = (w >> 1) << 6, n_off = (w & 1) << 6;
  if (t < 128) {
    const float* yp = Y + (size_t)(tm + t) * 384 + 128 + h * 16;
    float s = 0.f;
#pragma unroll
    for (int u = 0; u < 16; ++u) s += yp[u] * yp[u];
    diag_s[t] = 0.125f * s;
  }
  const int r = tm >> 11;
  const int c0 = tm & 2047;
  const float m = kmax[r * 8 + h];
  float bia[4];
#pragma unroll
  for (int ni = 0; ni < 4; ++ni) bia[ni] = bkf[h * 128 + n_off + ni * 16 + (lane & 15)];
  __syncthreads();
#pragma unroll
  for (int mi = 0; mi < 4; ++mi) {
#pragma unroll
    for (int i = 0; i < 4; ++i) {
      const int rl = m_off + mi * 16 + ((lane >> 4) << 2) + i;
      const int c = c0 + rl;
      const float dm = diag_s[rl] + m;
#pragma unroll
      for (int ni = 0; ni < 4; ++ni) {
        const int j = n_off + ni * 16 + (lane & 15);
        const float f = RATIO * (__expf(acc[mi][ni][i] + bia[ni] - dm) + EPSV);
        kf[((size_t)((h << 11) + c) << 10) + (r << 7) + j] = __float2bfloat16(f);
        kT[j * 136 + rl] = (__bf16)f;
      }
    }
  }
  __syncthreads();
  const int j2 = t >> 1, half = t & 1;
  __bf16* dst = (__bf16*)kfT + (((size_t)(h << 10) + (r << 7) + j2) << 11) + c0 + (half << 6);
  const __bf16* srcr = kT + j2 * 136 + (half << 6);
#pragma unroll
  for (int q8 = 0; q8 < 8; ++q8)
    *(bf16x8*)(dst + (q8 << 3)) = *(const bf16x8*)(srcr + (q8 << 3));
}

// ---------------- k_sum (row-reduce over kfT, coalesced) ----------------
__global__ __launch_bounds__(256) void k_ksum2(const __hip_bfloat16* __restrict__ kfT,
                                               float* __restrict__ ksum) {
  const int t = threadIdx.x, w = t >> 6, lane = t & 63;
  const int row = blockIdx.x * 4 + w;            // 0..8191 = h*1024 + d
  const __bf16* p = (const __bf16*)kfT + ((size_t)row << 11);
  float s = 0.f;
#pragma unroll
  for (int q = 0; q < 4; ++q) {
    bf16x8 v = *(const bf16x8*)(p + ((lane + (q << 6)) << 3));
#pragma unroll
    for (int j = 0; j < 8; ++j) s += (float)v[j];
  }
#pragma unroll
  for (int off = 1; off < 64; off <<= 1) s += __shfl_xor(s, off);
  if (lane == 0) ksum[row] = s;
}

__global__ __launch_bounds__(256) void k_dinv(
    const __hip_bfloat16* __restrict__ qf, const float* __restrict__ ksum,
    float* __restrict__ dinv) {
  const int t = threadIdx.x, w = t >> 6, lane = t & 63;
  const int h = blockIdx.y;
  const int c = blockIdx.x * 4 + w;
  const __bf16* qp = (const __bf16*)qf + ((size_t)((h << 11) + c) << 10);
  const float* ks = ksum + h * 1024;
  const int d0 = lane << 4;
  bf16x8 v0 = *(const bf16x8*)(qp + d0);
  bf16x8 v1 = *(const bf16x8*)(qp + d0 + 8);
  float s = 0.f;
#pragma unroll
  for (int j = 0; j < 8; ++j) s += (float)v0[j] * ks[d0 + j] + (float)v1[j] * ks[d0 + 8 + j];
#pragma unroll
  for (int off = 1; off < 64; off <<= 1) s += __shfl_xor(s, off);
  if (lane == 0) dinv[(h << 11) + c] = 1.0f / s;
}

// ---------------- attn GEMM: 256x256, BK=64, 4-phase/K-tile deep pipeline ----
#define SBAR() __builtin_amdgcn_s_barrier()
#define FEN()  do { asm volatile("" ::: "memory"); __builtin_amdgcn_sched_barrier(0); } while (0)
#define PRIO1() __builtin_amdgcn_s_setprio(1)
#define PRIO0() __builtin_amdgcn_s_setprio(0)
#define VMW4() do { asm volatile("s_waitcnt vmcnt(4)" ::: "memory"); } while (0)
#define VMW0() do { asm volatile("s_waitcnt vmcnt(0)" ::: "memory"); } while (0)

// LDS: A: buf*32768 + kh*16384 + row*64 + g*16   (granule g swizzled by (row>>1)&3)
//      B: +65536, same layout. Total 131072 bytes.
#define MFMA16(nlo) do {                                                      \
  _Pragma("unroll") for (int mi_ = 0; mi_ < 8; ++mi_)                         \
  _Pragma("unroll") for (int nj_ = 0; nj_ < 2; ++nj_)                         \
    acc[mi_][(nlo) + nj_] = __builtin_amdgcn_mfma_f32_16x16x32_bf16(          \
        aR[mi_], bR[nj_], acc[mi_][(nlo) + nj_], 0, 0, 0);                    \
} while (0)

__global__ __launch_bounds__(512, 2) void k_attn8(
    const __hip_bfloat16* __restrict__ qf, const __hip_bfloat16* __restrict__ kf,
    float* __restrict__ attn) {
  extern __shared__ __align__(128) char lds[];
  // bijective XCD swizzle: 512 blocks -> one head per XCD
  const int lid = blockIdx.x;
  const int swz = ((lid & 7) << 6) + (lid >> 3);
  const int h  = swz >> 6;
  const int tm = ((swz >> 3) & 7) << 8;
  const int tn = (swz & 7) << 8;
  const __hip_bfloat16* Ag = qf + ((size_t)h << 21);
  const __hip_bfloat16* Bg = kf + ((size_t)h << 21);

  const int t = threadIdx.x, wid = t >> 6, lane = t & 63;
  const int f = lane & 15;
  const int wr = wid >> 2, wc = wid & 3;
  const int swzg = (((lane >> 4) ^ ((f >> 1) & 3)) << 4);   // read-side granule swizzle (bytes)
  const int aoff = ((wr << 7) + f) * 64 + swzg;             // within A kh-region
  const int boff = 65536 + ((wc << 6) + f) * 64 + swzg;     // within B kh-region
  // staging constants (inverse swizzle on global source, linear LDS dest)
  const int srow = t >> 2;                                   // 0..127
  const int scol = (((t & 3) ^ ((t >> 3) & 3)) << 3);        // element offset in 32-col half
  const int sdst = wid << 10;                                // wave-uniform LDS offset

  f32x4 acc[8][4] = {};
  bf16x8 aR[8], bR[2];

  auto stageA = [&](int buf, int kh, int k0) {
    char* d = lds + buf * 32768 + kh * 16384 + sdst;
    const __hip_bfloat16* g = Ag + (size_t)(tm + srow) * 1024 + k0 + (kh << 5) + scol;
    gload16(g, d);
    gload16(g + 128 * 1024, d + 8192);
  };
  auto stageB = [&](int buf, int kh, int k0) {
    char* d = lds + 65536 + buf * 32768 + kh * 16384 + sdst;
    const __hip_bfloat16* g = Bg + (size_t)(tn + srow) * 1024 + k0 + (kh << 5) + scol;
    gload16(g, d);
    gload16(g + 128 * 1024, d + 8192);
  };

  // prologue: tile 0 -> buf0, issue order [Akh0, Bkh0, Akh1, Bkh1]
  stageA(0, 0, 0); stageB(0, 0, 0); stageA(0, 1, 0); stageB(0, 1, 0);
  VMW4();             // Akh0,Bkh0 resident
  SBAR(); FEN();

  for (int kt = 0; kt < 15; ++kt) {
    const int buf = kt & 1, nbuf = buf ^ 1;
    const int bo = buf * 32768;
    const int nk0 = (kt + 1) << 6;
    // P1: (ks0, ni0/1); stage A kh0(t+1)
#pragma unroll
    for (int mi = 0; mi < 8; ++mi) aR[mi] = *(const bf16x8*)(lds + bo + aoff + mi * 1024);
    bR[0] = *(const bf16x8*)(lds + bo + boff);
    bR[1] = *(const bf16x8*)(lds + bo + boff + 1024);
    stageA(nbuf, 0, nk0);
    PRIO1(); MFMA16(0); PRIO0();
    SBAR(); FEN();
    // P2: (ks0, ni2/3); stage B kh0(t+1); wait completes Akh1,Bkh1 of THIS tile
    bR[0] = *(const bf16x8*)(lds + bo + boff + 2048);
    bR[1] = *(const bf16x8*)(lds + bo + boff + 3072);
    stageB(nbuf, 0, nk0);
    PRIO1(); MFMA16(2); PRIO0();
    VMW4();
    SBAR(); FEN();
    // P3: (ks1, ni0/1); stage A kh1(t+1)
#pragma unroll
    for (int mi = 0; mi < 8; ++mi) aR[mi] = *(const bf16x8*)(lds + bo + 16384 + aoff + mi * 1024);
    bR[0] = *(const bf16x8*)(lds + bo + 16384 + boff);
    bR[1] = *(const bf16x8*)(lds + bo + 16384 + boff + 1024);
    stageA(nbuf, 1, nk0);
    PRIO1(); MFMA16(0); PRIO0();
    SBAR(); FEN();
    // P4: (ks1, ni2/3); stage B kh1(t+1); wait completes Akh0,Bkh0 of NEXT tile
    bR[0] = *(const bf16x8*)(lds + bo + 16384 + boff + 2048);
    bR[1] = *(const bf16x8*)(lds + bo + 16384 + boff + 3072);
    stageB(nbuf, 1, nk0);
    PRIO1(); MFMA16(2); PRIO0();
    VMW4();
    SBAR(); FEN();
  }
  { // epilogue: tile 15 in buf1, no staging; drain before ks1
    const int bo = 32768;
#pragma unroll
    for (int mi = 0; mi < 8; ++mi) aR[mi] = *(const bf16x8*)(lds + bo + aoff + mi * 1024);
    bR[0] = *(const bf16x8*)(lds + bo + boff);
    bR[1] = *(const bf16x8*)(lds + bo + boff + 1024);
    PRIO1(); MFMA16(0); PRIO0();
    bR[0] = *(const bf16x8*)(lds + bo + boff + 2048);
    bR[1] = *(const bf16x8*)(lds + bo + boff + 3072);
    PRIO1(); MFMA16(2); PRIO0();
    VMW0();
    SBAR(); FEN();
#pragma unroll
    for (int mi = 0; mi < 8; ++mi) aR[mi] = *(const bf16x8*)(lds + bo + 16384 + aoff + mi * 1024);
    bR[0] = *(const bf16x8*)(lds + bo + 16384 + boff);
    bR[1] = *(const bf16x8*)(lds + bo + 16384 + boff + 1024);
    PRIO1(); MFMA16(0); PRIO0();
    bR[0] = *(const bf16x8*)(lds + bo + 16384 + boff + 2048);
    bR[1] = *(const bf16x8*)(lds + bo + 16384 + boff + 3072);
    PRIO1(); MFMA16(2); PRIO0();
  }

  float* Cc = attn + ((size_t)h << 22);
  const int rbase = tm + (wr << 7) + ((lane >> 4) << 2);
  const int cbase = tn + (wc << 6) + f;
#pragma unroll
  for (int mi = 0; mi < 8; ++mi)
#pragma unroll
    for (int i = 0; i < 4; ++i) {
      float* rp = Cc + ((size_t)(rbase + mi * 16 + i) << 11) + cbase;
#pragma unroll
      for (int ni = 0; ni < 4; ++ni) rp[ni * 16] = acc[mi][ni][i];
    }
}

// ---------------- context GEMM (K-split) ----------------
__global__ __launch_bounds__(256) void k_ctx(
    const __hip_bfloat16* __restrict__ vfT, const __hip_bfloat16* __restrict__ kfT,
    float* __restrict__ ctxp) {
  __shared__ __align__(16) __bf16 As[4096], Bs[4096];
  const int z = blockIdx.z, h = z >> 2, kc = z & 3;
  const int tn = blockIdx.y << 7;
  f32x4 acc[4][4];
  ZERO_ACC(acc);
  gemm_core(vfT + ((size_t)h << 18) + (kc << 9), kfT + ((size_t)h << 21) + (kc << 9),
            2048, 2048, 512, 0, tn, As, Bs, acc);
  float* Cp = ctxp + ((size_t)(kc * 8 + h) << 17);
  const int t = threadIdx.x, w = t >> 6, lane = t & 63;
  const int m_off = (w >> 1) << 6, n_off = (w & 1) << 6;
#pragma unroll
  for (int mi = 0; mi < 4; ++mi)
#pragma unroll
    for (int i = 0; i < 4; ++i) {
      const int row = m_off + mi * 16 + ((lane >> 4) << 2) + i;
#pragma unroll
      for (int ni = 0; ni < 4; ++ni) {
        const int col = tn + n_off + ni * 16 + (lane & 15);
        Cp[((size_t)row << 10) + col] = acc[mi][ni][i];
      }
    }
}

__global__ void k_ctxred(const float* __restrict__ ctxp, __hip_bfloat16* __restrict__ ctxT) {
  const int i = blockIdx.x * 256 + threadIdx.x;
  const float s = ctxp[i] + ctxp[i + 1048576] + ctxp[i + 2097152] + ctxp[i + 3145728];
  ctxT[i] = __float2bfloat16(s);
}

// ---------------- out GEMM + D_inv scale + scatter ----------------
__global__ __launch_bounds__(256) void k_out(
    const __hip_bfloat16* __restrict__ qf, const __hip_bfloat16* __restrict__ ctxT,
    const float* __restrict__ dinv, float* __restrict__ outp) {
  __shared__ __align__(16) __bf16 As[4096], Bs[4096];
  const int h = blockIdx.z;
  const int tm = blockIdx.x << 7;
  f32x4 acc[4][4];
  ZERO_ACC(acc);
  gemm_core(qf + ((size_t)h << 21), ctxT + ((size_t)h << 17), 1024, 1024, 1024, tm, 0, As, Bs, acc);
  const int t = threadIdx.x, w = t >> 6, lane = t & 63;
  const int m_off = (w >> 1) << 6, n_off = (w & 1) << 6;
#pragma unroll
  for (int mi = 0; mi < 4; ++mi)
#pragma unroll
    for (int i = 0; i < 4; ++i) {
      const int row = tm + m_off + mi * 16 + ((lane >> 4) << 2) + i;
      const float dv = dinv[(h << 11) + row];
#pragma unroll
      for (int ni = 0; ni < 4; ++ni) {
        const int col = n_off + ni * 16 + (lane & 15);
        const int rb = col >> 4, tt = col & 15;
        outp[(((size_t)(rb << 11) + row) << 7) + (h << 4) + tt] = acc[mi][ni][i] * dv;
      }
    }
}

// ---------------- launch ----------------
extern "C" void kernel_launch(void* const* d_in, const int* in_sizes, int n_in,
                              void* d_out, int out_size, void* d_ws, size_t ws_size,
                              hipStream_t stream) {
  const float* x    = (const float*)d_in[0];
  const float* Wq   = (const float*)d_in[1];
  const float* bq   = (const float*)d_in[2];
  const float* Wk   = (const float*)d_in[3];
  const float* bk   = (const float*)d_in[4];
  const float* Wv   = (const float*)d_in[5];
  const float* bv   = (const float*)d_in[6];
  const float* proj = (const float*)d_in[7];
  if (ws_size < WS_NEED) return;

  char* ws = (char*)d_ws;
  __hip_bfloat16* xb   = (__hip_bfloat16*)(ws + OFF_XB);
  __hip_bfloat16* Wcat = (__hip_bfloat16*)(ws + OFF_WCAT);
  __hip_bfloat16* Mq   = (__hip_bfloat16*)(ws + OFF_MQ);
  __hip_bfloat16* Mk   = (__hip_bfloat16*)(ws + OFF_MK);
  float* bcat = (float*)(ws + OFF_BCAT);
  float* bqf  = (float*)(ws + OFF_BQF);
  float* bkf  = (float*)(ws + OFF_BKF);
  float* Y    = (float*)(ws + OFF_Y);
  __hip_bfloat16* qf  = (__hip_bfloat16*)(ws + OFF_QF);
  __hip_bfloat16* kf  = (__hip_bfloat16*)(ws + OFF_KF);
  __hip_bfloat16* kfT = (__hip_bfloat16*)(ws + OFF_KFT);
  __hip_bfloat16* vfT = (__hip_bfloat16*)(ws + OFF_VFT);
  float* kpart = (float*)(ws + OFF_KPART);
  float* kmax  = (float*)(ws + OFF_KMAX);
  float* ksum  = (float*)(ws + OFF_KSUM);
  float* dinv  = (float*)(ws + OFF_DINV);
  float* ctxp  = (float*)(ws + OFF_CTXP);
  __hip_bfloat16* ctxT = (__hip_bfloat16*)(ws + OFF_CTXT);

  float* outp = (float*)d_out;
  float* attn = (float*)d_out + 2097152;

  static int attr_done = 0;
  if (!attr_done) {
    (void)hipFuncSetAttribute((const void*)k_attn8,
                              hipFuncAttributeMaxDynamicSharedMemorySize, 131072);
    attr_done = 1;
  }

  k_prep<<<dim3(2048), dim3(256), 0, stream>>>(x, Wq, bq, Wk, bk, Wv, bv, proj,
                                               xb, Wcat, bcat, Mq, Mk, bqf, bkf);
  k_proj<<<dim3(128, 3), dim3(256), 0, stream>>>(xb, Wcat, bcat, Y);
  k_vft2<<<dim3(16, 8, 8), dim3(256), 0, stream>>>(Y, vfT);
  k_dashq<<<dim3(128, 8), dim3(256), 0, stream>>>(xb, Mq, bqf, Y, qf);
  k_dashk_max<<<dim3(128, 8), dim3(256), 0, stream>>>(xb, Mk, bkf, kpart);
  k_kmaxred<<<dim3(1), dim3(64), 0, stream>>>(kpart, kmax);
  k_dashk_feat<<<dim3(128, 8), dim3(256), 0, stream>>>(xb, Mk, bkf, Y, kmax, kf, kfT);
  k_ksum2<<<dim3(2048), dim3(256), 0, stream>>>(kfT, ksum);
  k_dinv<<<dim3(512, 8), dim3(256), 0, stream>>>(qf, ksum, dinv);
  k_attn8<<<dim3(512), dim3(512), 131072, stream>>>(qf, kf, attn);
  k_ctx<<<dim3(1, 8, 32), dim3(256), 0, stream>>>(vfT, kfT, ctxp);
  k_ctxred<<<dim3(4096), dim3(256), 0, stream>>>(ctxp, ctxT);
  k_out<<<dim3(16, 1, 8), dim3(256), 0, stream>>>(qf, ctxT, dinv, outp);
}